// Round 13
// baseline (178.330 us; speedup 1.0000x reference)
//
#include <hip/hip_runtime.h>
#include <stdint.h>

typedef unsigned short u16;
typedef __bf16 bf16x8 __attribute__((ext_vector_type(8)));
typedef float f32x4 __attribute__((ext_vector_type(4)));
typedef unsigned int u32x4 __attribute__((ext_vector_type(4)));

__device__ __forceinline__ u16 f2bf(float f) {
  uint32_t u = __float_as_uint(f);
  u += 0x7FFFu + ((u >> 16) & 1u);   // RNE
  return (u16)(u >> 16);
}
__device__ __forceinline__ float bf2f(u16 h) {
  return __uint_as_float(((uint32_t)h) << 16);
}
__device__ __forceinline__ float fsqrt(float x) {
  float r; asm("v_sqrt_f32 %0, %1" : "=v"(r) : "v"(x)); return r;
}
__device__ __forceinline__ float fexp2(float x) {
  float r; asm("v_exp_f32 %0, %1" : "=v"(r) : "v"(x)); return r;
}
__device__ __forceinline__ void gld16(const void* g, void* lds) {
  __builtin_amdgcn_global_load_lds(
      (const __attribute__((address_space(1))) uint32_t*)g,
      (__attribute__((address_space(3))) uint32_t*)lds, 16, 0, 0);
}
__device__ __forceinline__ f32x4 mfma16(u32x4 a, u32x4 b, f32x4 c) {
  return __builtin_amdgcn_mfma_f32_16x16x32_bf16(
      __builtin_bit_cast(bf16x8, a), __builtin_bit_cast(bf16x8, b), c, 0, 0, 0);
}

// ---- fused prep: convx (X f32->bf16) + convw (W transpose+convert) + trig ----
__global__ __launch_bounds__(256) void prep_kernel(
    const float* __restrict__ real, const float* __restrict__ imag,
    u16* __restrict__ Xr, u16* __restrict__ Xi,
    const float* __restrict__ w0, const float* __restrict__ w1,
    const float* __restrict__ w2, const float* __restrict__ w3,
    const float* __restrict__ w4, const float* __restrict__ w5,
    const float* __restrict__ w6, const float* __restrict__ w7,
    u16* __restrict__ WtAll,
    const float* __restrict__ rotf, const float* __restrict__ phase,
    float* __restrict__ T) {
  __shared__ float Lt[64][65];
  int bid = blockIdx.x;
  int tid = threadIdx.x;
  if (bid < 2048) {
    // ---- convx: plain row-major f32 -> bf16 ----
    int u = bid * 256 + tid;                 // 0..524287
    int a = u >> 18;
    int r = u & 262143;                      // 8-elem unit index
    const float* src = (a ? imag : real) + (size_t)r * 8;
    u16* dst = (a ? Xi : Xr) + (size_t)r * 8;
    f32x4 v0 = *(const f32x4*)(src);
    f32x4 v1 = *(const f32x4*)(src + 4);
    union { u16 h[8]; u32x4 v; } o;
#pragma unroll
    for (int e = 0; e < 4; ++e) { o.h[e] = f2bf(v0[e]); o.h[4 + e] = f2bf(v1[e]); }
    *(u32x4*)dst = o.v;
  } else if (bid < 4096) {
    // ---- convw: W f32 [K][N] -> Wt bf16 [N][K] ----
    int wid = bid - 2048;
    int z = wid >> 8;
    int rem = wid & 255;
    int n0 = (rem & 15) * 64, k0 = (rem >> 4) * 64;
    const float* W = (z == 0) ? w0 : (z == 1) ? w1 : (z == 2) ? w2 : (z == 3) ? w3
                   : (z == 4) ? w4 : (z == 5) ? w5 : (z == 6) ? w6 : w7;
    u16* Wt = WtAll + (size_t)z * (1024 * 1024);
#pragma unroll
    for (int it = 0; it < 4; ++it) {
      int idx = it * 256 + tid;              // 0..1023 float4 units
      int kr = idx >> 4, nc = (idx & 15) * 4;
      f32x4 v = *(const f32x4*)(W + (size_t)(k0 + kr) * 1024 + n0 + nc);
#pragma unroll
      for (int e = 0; e < 4; ++e) Lt[kr][nc + e] = v[e];
    }
    __syncthreads();
#pragma unroll
    for (int it = 0; it < 2; ++it) {
      int idx = it * 256 + tid;              // 0..511
      int nr = idx >> 3, sl = idx & 7;
      union { u16 h[8]; u32x4 v; } o;
#pragma unroll
      for (int e = 0; e < 8; ++e) o.h[e] = f2bf(Lt[sl * 8 + e][nr]);
      *(u32x4*)(Wt + (size_t)(n0 + nr) * 1024 + k0 + sl * 8) = o.v;
    }
  } else {
    // ---- trig tables: rope cos/sin [1024][16], phase cos/sin [16][64] ----
    int id = (bid - 4096) * 256 + tid;
    if (id < 16384) {
      int s = id >> 4, jj = id & 15;
      float sn, cs;
      sincosf((float)s * rotf[jj], &sn, &cs);
      T[id] = cs;
      T[16384 + id] = sn;
    } else if (id < 16384 + 1024) {
      int p = id - 16384;
      float sn, cs;
      sincosf(phase[p], &sn, &cs);
      T[32768 + p] = cs;
      T[33792 + p] = sn;
    }
  }
}

// ---- 256x128 MFMA GEMM, BK=32 counted-vmcnt dbuf, 32 MFMA/barrier ----
// LDS: As 2x16KB (256 rows x 64B), Bs 2x8KB (128 rows x 64B); 48KB total.
// Swizzle (r11-verified): source k-slot = (tid&3)^((row>>1)&3), LDS linear,
// read at xoff = (lh^((lr>>1)&3))<<4 (row-independent).
__device__ __forceinline__ void gemm_tile(const u16* __restrict__ A, const u16* __restrict__ W,
                                          const float* __restrict__ bias,
                                          u16* __restrict__ outB, float* __restrict__ outF,
                                          int bx, int by) {
  __shared__ __align__(16) u16 As[2][256 * 32];
  __shared__ __align__(16) u16 Bs[2][128 * 32];
  int tid = threadIdx.x, l = tid & 63, w = tid >> 6;
  int lr = l & 15, lh = l >> 4;
  int m0 = by * 256, n0 = bx * 128;
  f32x4 acc[4][8];
#pragma unroll
  for (int mi = 0; mi < 4; ++mi)
#pragma unroll
    for (int nj = 0; nj < 8; ++nj) acc[mi][nj] = f32x4{0.f, 0.f, 0.f, 0.f};

  // stage addressing: row = tid>>2 (+c*64); source pre-swizzled, LDS linear
  int srow = tid >> 2;
  int sslot = (tid & 3) ^ ((srow >> 1) & 3);
  const u16* aA = A + (size_t)(m0 + srow) * 1024 + sslot * 8;
  const u16* aW = W + (size_t)(n0 + srow) * 1024 + sslot * 8;

  // stage K-tile kt into buffer buf: 6 gld16 per thread (4 A + 2 W)
  auto stage = [&](int buf, int kt) {
    const u16* pA = aA + kt * 32;
    const u16* pW = aW + kt * 32;
    char* dA = (char*)As[buf] + tid * 16;
    char* dB = (char*)Bs[buf] + tid * 16;
    gld16(pA, dA);
    gld16(pA + 64 * 1024, dA + 4096);
    gld16(pA + 128 * 1024, dA + 8192);
    gld16(pA + 192 * 1024, dA + 12288);
    gld16(pW, dB);
    gld16(pW + 64 * 1024, dB + 4096);
  };

  stage(0, 0);                               // prologue

  // read-side swizzled k-slot offset (row-independent)
  int xoff = (lh ^ ((lr >> 1) & 3)) << 4;

  for (int kt = 0; kt < 32; ++kt) {
    int cur = kt & 1;
    if (kt < 31) {
      stage(cur ^ 1, kt + 1);                // prefetch stays in flight
      asm volatile("s_waitcnt vmcnt(6)" ::: "memory");   // cur's 6 loads done
    } else {
      asm volatile("s_waitcnt vmcnt(0)" ::: "memory");
    }
    __builtin_amdgcn_sched_barrier(0);
    asm volatile("s_barrier" ::: "memory");  // all waves' cur loads visible

    const char* cA = (const char*)As[cur];
    const char* cB = (const char*)Bs[cur];
    u32x4 af[4];
#pragma unroll
    for (int mi = 0; mi < 4; ++mi) {
      int row = w * 64 + mi * 16 + lr;
      af[mi] = *(const u32x4*)(cA + row * 64 + xoff);
    }
#pragma unroll
    for (int nj = 0; nj < 8; ++nj) {
      int row = nj * 16 + lr;
      u32x4 bf = *(const u32x4*)(cB + row * 64 + xoff);
#pragma unroll
      for (int mi = 0; mi < 4; ++mi)
        acc[mi][nj] = mfma16(af[mi], bf, acc[mi][nj]);
    }
    asm volatile("s_barrier" ::: "memory");  // reads done before buf overwrite
  }
#pragma unroll
  for (int nj = 0; nj < 8; ++nj) {
    int col = n0 + nj * 16 + lr;
    float bv = bias[col];
#pragma unroll
    for (int mi = 0; mi < 4; ++mi)
#pragma unroll
      for (int rr = 0; rr < 4; ++rr) {
        int row = m0 + w * 64 + mi * 16 + 4 * lh + rr;
        float v = acc[mi][nj][rr] + bv;
        if (outF) outF[(size_t)row * 1024 + col] = v;
        else      outB[(size_t)row * 1024 + col] = f2bf(v);
      }
  }
}

__global__ __launch_bounds__(256) void gemm_proj_kernel(
    const u16* __restrict__ Xr, const u16* __restrict__ Xi, const u16* __restrict__ Wt,
    const float* b0, const float* b1, const float* b2,
    const float* b3, const float* b4, const float* b5,
    u16* __restrict__ qkv) {
  // XCD-aware bijective remap: 384 blocks = 8 XCDs x 48
  int lin = ((int)blockIdx.z * 8 + blockIdx.y) * 8 + blockIdx.x;  // 0..383
  int nl = (lin & 7) * 48 + (lin >> 3);
  int z = nl >> 6;
  int rem = nl & 63;
  int my = rem >> 3, nx = rem & 7;
  const u16* A = (z < 3) ? Xr : Xi;
  const u16* W = Wt + (size_t)z * (1024 * 1024);
  const float* bias = (z == 0) ? b0 : (z == 1) ? b1 : (z == 2) ? b2
                    : (z == 3) ? b3 : (z == 4) ? b4 : b5;
  u16* out = qkv + (size_t)z * (2048 * 1024);
  gemm_tile(A, W, bias, out, nullptr, nx, my);
}

__global__ __launch_bounds__(256) void gemm_out_kernel(
    const u16* __restrict__ O, const u16* __restrict__ Wt2,
    const float* br, const float* bi, float* __restrict__ dout) {
  int lin = ((int)blockIdx.z * 8 + blockIdx.y) * 8 + blockIdx.x;  // 0..127
  int nl = (lin & 7) * 16 + (lin >> 3);
  int z = nl >> 6;
  int rem = nl & 63;
  int my = rem >> 3, nx = rem & 7;
  gemm_tile(O + (size_t)z * (2048 * 1024), Wt2 + (size_t)z * (1024 * 1024),
            z ? bi : br, nullptr, dout + (size_t)z * (2048 * 1024), nx, my);
}

// ---- rope + head-mix + phase (table-driven); Q/K/V relayout to [B,H,S,64] ----
__global__ __launch_bounds__(256) void transform_kernel(
    const u16* __restrict__ qkv, const float* __restrict__ ent,
    const float* __restrict__ T,
    u16* __restrict__ Qr, u16* __restrict__ Qi, u16* __restrict__ Kr,
    u16* __restrict__ Ki, u16* __restrict__ Vr, u16* __restrict__ Vi) {
  __shared__ float Lqr[16][65], Lqi[16][65], Lkr[16][65], Lki[16][65];
  __shared__ float sent[256];
  int tid = threadIdx.x;
  int bs = blockIdx.x;
  int b = bs >> 10, s = bs & 1023;
  sent[tid] = ent[tid];
  const u16* qr_raw = qkv;
  const u16* kr_raw = qkv + (size_t)1 * 2048 * 1024;
  const u16* vr_raw = qkv + (size_t)2 * 2048 * 1024;
  const u16* qi_raw = qkv + (size_t)3 * 2048 * 1024;
  const u16* ki_raw = qkv + (size_t)4 * 2048 * 1024;
  const u16* vi_raw = qkv + (size_t)5 * 2048 * 1024;
  size_t rowoff = (size_t)bs * 1024;
#pragma unroll
  for (int it = 0; it < 2; ++it) {
    int u = it * 256 + tid;                  // 0..511 : (head, pair)
    int hh = u >> 5, j = u & 31;
    int base = hh * 64 + 2 * j;
    uint32_t aqr = *(const uint32_t*)(qr_raw + rowoff + base);
    uint32_t aqi = *(const uint32_t*)(qi_raw + rowoff + base);
    uint32_t akr = *(const uint32_t*)(kr_raw + rowoff + base);
    uint32_t aki = *(const uint32_t*)(ki_raw + rowoff + base);
    float qr0 = bf2f((u16)aqr), qr1 = bf2f((u16)(aqr >> 16));
    float qi0 = bf2f((u16)aqi), qi1 = bf2f((u16)(aqi >> 16));
    float kr0 = bf2f((u16)akr), kr1 = bf2f((u16)(akr >> 16));
    float ki0 = bf2f((u16)aki), ki1 = bf2f((u16)(aki >> 16));
    if (j < 16) {
      float cs = T[s * 16 + j];
      float sn = T[16384 + s * 16 + j];
      float t0;
      t0 = qr0; qr0 = t0 * cs - qr1 * sn; qr1 = qr1 * cs + t0 * sn;
      t0 = qi0; qi0 = t0 * cs - qi1 * sn; qi1 = qi1 * cs + t0 * sn;
      t0 = kr0; kr0 = t0 * cs - kr1 * sn; kr1 = kr1 * cs + t0 * sn;
      t0 = ki0; ki0 = t0 * cs - ki1 * sn; ki1 = ki1 * cs + t0 * sn;
    }
    int d0 = 2 * j;
    Lqr[hh][d0] = qr0; Lqr[hh][d0 + 1] = qr1;
    Lqi[hh][d0] = qi0; Lqi[hh][d0 + 1] = qi1;
    Lkr[hh][d0] = kr0; Lkr[hh][d0 + 1] = kr1;
    Lki[hh][d0] = ki0; Lki[hh][d0 + 1] = ki1;
  }
  __syncthreads();
#pragma unroll
  for (int it = 0; it < 4; ++it) {
    int u = it * 256 + tid;                  // 0..1023 : (x-head, d)
    int x = u >> 6, d = u & 63;
    float mqr = 0.f, mqi = 0.f, mkr = 0.f, mki = 0.f;
#pragma unroll
    for (int hh = 0; hh < 16; ++hh) {
      float e = sent[hh * 16 + x];
      mqr += Lqr[hh][d] * e; mqi += Lqi[hh][d] * e;
      mkr += Lkr[hh][d] * e; mki += Lki[hh][d] * e;
    }
    float pc_ = T[32768 + x * 64 + d];
    float ps_ = T[33792 + x * 64 + d];
    float oqr = (mqr * pc_ - mqi * ps_) * 0.125f;  // fold 1/sqrt(64)
    float oqi = (mqr * ps_ + mqi * pc_) * 0.125f;
    float okr = mkr * pc_ - mki * ps_;
    float oki = mkr * ps_ + mki * pc_;
    size_t obase = ((size_t)(b * 16 + x) * 1024 + s) * 64;
    Qr[obase + d] = f2bf(oqr);
    Qi[obase + d] = f2bf(oqi);
    int dsw = (d & 7) | ((((d >> 3) ^ s) & 7) << 3);
    Kr[obase + dsw] = f2bf(okr);
    Ki[obase + dsw] = f2bf(oki);
  }
  {
    int u = tid;                             // 0..255 : (comp, head, slot)
    int comp = u >> 7, hh = (u >> 3) & 15, sl = u & 7;
    const u16* src = comp ? vi_raw : vr_raw;
    u16* dst = comp ? Vi : Vr;
    u32x4 vv = *(const u32x4*)(src + rowoff + hh * 64 + sl * 8);
    *(u32x4*)(dst + ((size_t)(b * 16 + hh) * 1024 + s) * 64 + sl * 8) = vv;
  }
}

// ---- V [B,H,S,64] -> VT [B,H,64,S] transposed + swizzled ----
__global__ __launch_bounds__(256) void transv_kernel(const u16* __restrict__ Vr,
                                                     const u16* __restrict__ Vi,
                                                     u16* __restrict__ VTr,
                                                     u16* __restrict__ VTi) {
  int bid = blockIdx.x;
  int comp = bid >> 9, bh = (bid >> 4) & 31, t = bid & 15;
  const u16* src = (comp ? Vi : Vr) + ((size_t)bh * 1024 + t * 64) * 64;
  u16* dst = (comp ? VTi : VTr) + (size_t)bh * 65536;
  __shared__ __align__(16) u16 Lt[64][72];
  int tid = threadIdx.x;
#pragma unroll
  for (int it = 0; it < 2; ++it) {
    int i = it * 256 + tid;
    int r = i >> 3, sl = i & 7;
    *(u32x4*)(&Lt[r][sl * 8]) = *(const u32x4*)(src + r * 64 + sl * 8);
  }
  __syncthreads();
#pragma unroll
  for (int it = 0; it < 2; ++it) {
    int i = it * 256 + tid;
    int d = i >> 3, sl = i & 7;
    union { u16 h[8]; u32x4 v; } o;
#pragma unroll
    for (int e = 0; e < 8; ++e) o.h[e] = Lt[sl * 8 + e][d];
    int sl2 = sl ^ (d & 7);
    *(u32x4*)(dst + (size_t)d * 1024 + t * 64 + sl2 * 8) = o.v;
  }
}

// ---- flash attention, uniform 4-tile chunks, partial outputs (base-2) ----
__global__ __launch_bounds__(256) void attn_kernel(
    const u16* __restrict__ Qr, const u16* __restrict__ Qi,
    const u16* __restrict__ Kr, const u16* __restrict__ Ki,
    const u16* __restrict__ VTr, const u16* __restrict__ VTi,
    const float* __restrict__ strength, const float* __restrict__ temp,
    u16* __restrict__ por0, u16* __restrict__ por1,
    u16* __restrict__ por2, u16* __restrict__ por3,
    u16* __restrict__ poi0, u16* __restrict__ poi1,
    u16* __restrict__ poi2, u16* __restrict__ poi3,
    float* __restrict__ Pm, float* __restrict__ Pl) {
  // 40KB: Kr,Ki,VrT,ViT 8KB each + 4x 2KB per-wave P
  __shared__ __align__(16) u16 smem[20480];
  char* sb = (char*)smem;
  const int PO = 32768;
  int tid = threadIdx.x, l = tid & 63, w = tid >> 6;
  int lr = l & 15, lh = l >> 4;
  // decode: XCD-local bh; chunks cc ascending = qb descending (big first)
  int id = blockIdx.x;                       // 0..1279
  int x = id & 7, j = id >> 3;               // j 0..159
  int bh = x + 8 * (j & 3);
  int cc = j >> 2;                           // 0..39
  int qb, sp;
  if (cc < 16)      { qb = 15 - (cc >> 2); sp = cc & 3; }
  else if (cc < 28) { int r = cc - 16; int q3 = r / 3; qb = 11 - q3; sp = r - 3 * q3; }
  else if (cc < 36) { int r = cc - 28; qb = 7 - (r >> 1); sp = r & 1; }
  else              { qb = 39 - cc; sp = 0; }
  int q0 = qb * 64;
  int t0 = sp * 4, t1 = min(qb + 1, t0 + 4);
  int b = bh >> 4; (void)b;
  u16* POr = (sp == 0) ? por0 : (sp == 1) ? por1 : (sp == 2) ? por2 : por3;
  u16* POi = (sp == 0) ? poi0 : (sp == 1) ? poi1 : (sp == 2) ? poi2 : poi3;

  float g = 1.f / (1.f + __expf(-strength[0]));
  float tt = fmaxf(temp[0], 0.01f);
  float gt2 = g / tt * 1.4426950408889634f;  // base-2 logit domain

  size_t qbase = ((size_t)bh * 1024 + q0 + w * 16 + lr) * 64 + lh * 8;
  u32x4 qrF[2], qiF[2], nqrF[2];
#pragma unroll
  for (int kk = 0; kk < 2; ++kk) {
    qrF[kk] = *(const u32x4*)(Qr + qbase + kk * 32);
    qiF[kk] = *(const u32x4*)(Qi + qbase + kk * 32);
    nqrF[kk] = qrF[kk] ^ 0x80008000u;
  }
  f32x4 o_r[4], o_i[4];
#pragma unroll
  for (int n = 0; n < 4; ++n) { o_r[n] = f32x4{0,0,0,0}; o_i[n] = f32x4{0,0,0,0}; }
  float m_run[4], l_run[4];
#pragma unroll
  for (int rr = 0; rr < 4; ++rr) { m_run[rr] = -__builtin_inff(); l_run[rr] = 0.f; }

  // hoisted per-wave stage pointers (advance by constant per tile)
  const u16* gK = ((w == 1) ? Ki : Kr) + ((size_t)bh * 1024 + t0 * 64) * 64 + l * 8;
  char* ldK = sb + (w == 1 ? 8192 : 0);
  const u16* gV = ((w == 3) ? VTi : VTr) + (size_t)bh * 65536 + t0 * 64 +
                  (l >> 3) * 1024 + (l & 7) * 8;
  char* ldV = sb + (w == 3 ? 24576 : 16384);

  for (int t = t0; t < t1; ++t) {
    if (w < 2) {
#pragma unroll
      for (int c = 0; c < 8; ++c) gld16(gK + c * 512, ldK + c * 1024);
      gK += 4096;
    } else {
#pragma unroll
      for (int c = 0; c < 8; ++c) gld16(gV + c * 8192, ldV + c * 1024);
      gV += 64;
    }
    __syncthreads();

    f32x4 sr[4], si[4];
#pragma unroll
    for (int n = 0; n < 4; ++n) { sr[n] = f32x4{0,0,0,0}; si[n] = f32x4{0,0,0,0}; }
    __builtin_amdgcn_s_setprio(1);
#pragma unroll
    for (int kk = 0; kk < 2; ++kk) {
#pragma unroll
      for (int n = 0; n < 4; ++n) {
        int kv = n * 16 + lr;
        int xoff = (kk * 64 + lh * 16) ^ ((kv & 7) << 4);
        u32x4 fkr = *(const u32x4*)(sb + kv * 128 + xoff);
        u32x4 fki = *(const u32x4*)(sb + 8192 + kv * 128 + xoff);
        sr[n] = mfma16(qrF[kk], fkr, sr[n]);
        sr[n] = mfma16(qiF[kk], fki, sr[n]);
        si[n] = mfma16(qiF[kk], fkr, si[n]);
        si[n] = mfma16(nqrF[kk], fki, si[n]);
      }
    }
    __builtin_amdgcn_s_setprio(0);

    float pl_[4][4], pm[4];
#pragma unroll
    for (int rr = 0; rr < 4; ++rr) pm[rr] = -__builtin_inff();
    bool diag = (t == qb);
#pragma unroll
    for (int n = 0; n < 4; ++n)
#pragma unroll
      for (int rr = 0; rr < 4; ++rr) {
        float a = sr[n][rr], ci = si[n][rr];
        float mag = fsqrt(a * a + ci * ci + 1e-6f) * gt2;
        if (diag) {
          if (n * 16 + lr > w * 16 + 4 * lh + rr) mag = -__builtin_inff();
        }
        pl_[n][rr] = mag;
        pm[rr] = fmaxf(pm[rr], mag);
      }
#pragma unroll
    for (int mk = 1; mk <= 8; mk <<= 1)
#pragma unroll
      for (int rr = 0; rr < 4; ++rr)
        pm[rr] = fmaxf(pm[rr], __shfl_xor(pm[rr], mk));

    // defer-max: skip rescale when tile max didn't grow past 8 nats (11.54 bits)
    bool defer = true;
#pragma unroll
    for (int rr = 0; rr < 4; ++rr) defer = defer && (pm[rr] - m_run[rr] <= 11.54f);
    bool noresc = __all(defer ? 1 : 0);
    float fr[4];
    if (!noresc) {
#pragma unroll
      for (int rr = 0; rr < 4; ++rr) {
        float mnew = fmaxf(m_run[rr], pm[rr]);
        fr[rr] = fexp2(m_run[rr] - mnew);
        m_run[rr] = mnew;
      }
    }
    float rs[4];
#pragma unroll
    for (int rr = 0; rr < 4; ++rr) rs[rr] = 0.f;
#pragma unroll
    for (int n = 0; n < 4; ++n)
#pragma unroll
      for (int rr = 0; rr < 4; ++rr) {
        float p = fexp2(pl_[n][rr] - m_run[rr]);
        pl_[n][rr] = p;
        rs[rr] += p;
      }
#pragma unroll
    for (int mk = 1; mk <= 8; mk <<= 1)
#pragma unroll
      for (int rr = 0; rr < 4; ++rr)
        rs[rr] += __shfl_xor(rs[rr], mk);
    if (!noresc) {
#pragma unroll
      for (int rr = 0; rr < 4; ++rr) l_run[rr] = l_run[rr] * fr[rr] + rs[rr];
#pragma unroll
      for (int n = 0; n < 4; ++n)
#pragma unroll
        for (int rr = 0; rr < 4; ++rr) { o_r[n][rr] *= fr[rr]; o_i[n][rr] *= fr[rr]; }
    } else {
#pragma unroll
      for (int rr = 0; rr < 4; ++rr) l_run[rr] += rs[rr];
    }

    char* pw = sb + PO + w * 2048;           // per-wave P tile 16x64 bf16
#pragma unroll
    for (int n = 0; n < 4; ++n)
#pragma unroll
      for (int rr = 0; rr < 4; ++rr) {
        int row = 4 * lh + rr, col = n * 16 + lr;
        int by = row * 128 + ((col & 7) * 2) + ((((col >> 3) ^ row) & 7) << 4);
        *(u16*)(pw + by) = f2bf(pl_[n][rr]);
      }
    u32x4 pf[2];
#pragma unroll
    for (int kk = 0; kk < 2; ++kk)
      pf[kk] = *(const u32x4*)(pw + lr * 128 + ((kk * 64 + lh * 16) ^ ((lr & 7) << 4)));
    __builtin_amdgcn_s_setprio(1);
#pragma unroll
    for (int kk = 0; kk < 2; ++kk)
#pragma unroll
      for (int n = 0; n < 4; ++n) {
        int dl = n * 16 + lr;
        int xoff = (kk * 64 + lh * 16) ^ ((dl & 7) << 4);
        u32x4 fvr = *(const u32x4*)(sb + 16384 + dl * 128 + xoff);
        u32x4 fvi = *(const u32x4*)(sb + 24576 + dl * 128 + xoff);
        o_r[n] = mfma16(pf[kk], fvr, o_r[n]);
        o_i[n] = mfma16(pf[kk], fvi, o_i[n]);
      }
    __builtin_amdgcn_s_setprio(0);
    __syncthreads();                         // LDS free for next tile
  }

  // epilogue: unnormalized partials (Pm in base-2 domain)
  size_t pbase = ((size_t)bh * 1024 + q0 + w * 16 + 4 * lh) * 64;
#pragma unroll
  for (int n = 0; n < 4; ++n)
#pragma unroll
    for (int rr = 0; rr < 4; ++rr) {
      POr[pbase + rr * 64 + n * 16 + lr] = f2bf(o_r[n][rr]);
      POi[pbase + rr * 64 + n * 16 + lr] = f2bf(o_i[n][rr]);
    }
  if (lr == 0) {
    size_t mbase = (size_t)sp * 32768 + (size_t)bh * 1024 + q0 + w * 16 + 4 * lh;
#pragma unroll
    for (int rr = 0; rr < 4; ++rr) {
      Pm[mbase + rr] = m_run[rr];
      Pl[mbase + rr] = l_run[rr];
    }
  }
}

// ---- combine split partials -> normalized O (base-2 Pm domain) ----
__global__ __launch_bounds__(256) void combine_kernel(
    const u16* __restrict__ por0, const u16* __restrict__ por1,
    const u16* __restrict__ por2, const u16* __restrict__ por3,
    const u16* __restrict__ poi0, const u16* __restrict__ poi1,
    const u16* __restrict__ poi2, const u16* __restrict__ poi3,
    const float* __restrict__ Pm, const float* __restrict__ Pl,
    u16* __restrict__ Or, u16* __restrict__ Oi) {
  int bid = blockIdx.x;                      // 512
  int bh = bid >> 4, rg = bid & 15;
  int b = bh >> 4, h = bh & 15;
  int ns = (rg >> 2) + 1;                    // valid splits for this q-group
  int tid = threadIdx.x;
  int row = tid >> 2, q = tid & 3;
  int s = rg * 64 + row;
  size_t ro = (size_t)bh * 1024 + s;
  const u16* PR[4] = {por0, por1, por2, por3};
  const u16* PI[4] = {poi0, poi1, poi2, poi3};
  float msp[4], lsp[4], csw[4];
  float M = -__builtin_inff();
#pragma unroll
  for (int sp = 0; sp < 4; ++sp) {
    if (sp < ns) {
      msp[sp] = Pm[ro + (size_t)sp * 32768];
      lsp[sp] = Pl[ro + (size_t)sp * 32768];
      M = fmaxf(M, msp[sp]);
    }
  }
  float lt = 0.f;
#pragma unroll
  for (int sp = 0; sp < 4; ++sp) {
    if (sp < ns) { csw[sp] = fexp2(msp[sp] - M); lt += lsp[sp] * csw[sp]; }
    else csw[sp] = 0.f;
  }
  float inv = 1.f / lt;
#pragma unroll
  for (int sp = 0; sp < 4; ++sp) csw[sp] *= inv;
  size_t obase = ro * 64;
#pragma unroll
  for (int g = 0; g < 2; ++g) {
    int d = q * 16 + g * 8;
    float accr[8], acci[8];
#pragma unroll
    for (int e = 0; e < 8; ++e) { accr[e] = 0.f; acci[e] = 0.f; }
#pragma unroll
    for (int sp = 0; sp < 4; ++sp) {
      if (sp < ns) {
        union { u16 h[8]; u32x4 v; } ar, ai;
        ar.v = *(const u32x4*)(PR[sp] + obase + d);
        ai.v = *(const u32x4*)(PI[sp] + obase + d);
#pragma unroll
        for (int e = 0; e < 8; ++e) {
          accr[e] += csw[sp] * bf2f(ar.h[e]);
          acci[e] += csw[sp] * bf2f(ai.h[e]);
        }
      }
    }
    union { u16 h[8]; u32x4 v; } outr, outi;
#pragma unroll
    for (int e = 0; e < 8; ++e) { outr.h[e] = f2bf(accr[e]); outi.h[e] = f2bf(acci[e]); }
    size_t oo = ((size_t)b * 1024 + s) * 1024 + h * 64 + d;
    *(u32x4*)(Or + oo) = outr.v;
    *(u32x4*)(Oi + oo) = outi.v;
  }
}

extern "C" void kernel_launch(void* const* d_in, const int* in_sizes, int n_in,
                              void* d_out, int out_size, void* d_ws, size_t ws_size,
                              hipStream_t stream) {
  (void)in_sizes; (void)n_in; (void)out_size; (void)ws_size;
  const float* real = (const float*)d_in[0];
  const float* imag = (const float*)d_in[1];
  const float* bq_r = (const float*)d_in[3];
  const float* bk_r = (const float*)d_in[5];
  const float* bv_r = (const float*)d_in[7];
  const float* bq_i = (const float*)d_in[9];
  const float* bk_i = (const float*)d_in[11];
  const float* bv_i = (const float*)d_in[13];
  const float* bo_r = (const float*)d_in[15];
  const float* bo_i = (const float*)d_in[17];
  const float* phase = (const float*)d_in[18];
  const float* ent = (const float*)d_in[19];
  const float* rotf = (const float*)d_in[20];
  const float* strength = (const float*)d_in[21];
  const float* temp = (const float*)d_in[22];

  u16* ws = (u16*)d_ws;
  const size_t M1 = 1024 * 1024, M2 = 2048 * 1024;
  u16* Xr  = ws;
  u16* Xi  = Xr + M2;
  u16* Wt  = Xi + M2;            // 8 * M1
  u16* qkv = Wt + 8 * M1;        // 6 * M2
  u16* Qr  = qkv + 6 * M2;
  u16* Qi  = Qr + M2;
  u16* Kr  = Qi + M2;
  u16* Ki  = Kr + M2;
  u16* Vr  = Ki + M2;
  u16* Vi  = Vr + M2;
  u16* VTr = Vi + M2;
  u16* VTi = VTr + M2;
  u16* Or  = VTi + M2;
  u16* Oi  = Or + M2;
  // overlays: partials on dead qkv/Vr/Vi; Pm/Pl on dead Xr; tables on Oi
  u16* por0 = qkv;
  u16* por1 = qkv + M2;
  u16* por2 = qkv + 2 * M2;
  u16* por3 = qkv + 3 * M2;
  u16* poi0 = qkv + 4 * M2;
  u16* poi1 = qkv + 5 * M2;
  u16* poi2 = Vr;
  u16* poi3 = Vi;
  float* Pm = (float*)Xr;
  float* Pl = Pm + 131072;
  float* TBL = (float*)Oi;       // 140KB of trig tables (dead until combine)

  prep_kernel<<<4164, 256, 0, stream>>>(
      real, imag, Xr, Xi,
      (const float*)d_in[2],  (const float*)d_in[4],  (const float*)d_in[6],
      (const float*)d_in[8],  (const float*)d_in[10], (const float*)d_in[12],
      (const float*)d_in[14], (const float*)d_in[16], Wt,
      rotf, phase, TBL);
  gemm_proj_kernel<<<dim3(8, 8, 6), 256, 0, stream>>>(Xr, Xi, Wt, bq_r, bk_r, bv_r,
                                                      bq_i, bk_i, bv_i, qkv);
  transform_kernel<<<2048, 256, 0, stream>>>(qkv, ent, TBL, Qr, Qi, Kr, Ki, Vr, Vi);
  transv_kernel<<<1024, 256, 0, stream>>>(Vr, Vi, VTr, VTi);
  attn_kernel<<<1280, 256, 0, stream>>>(Qr, Qi, Kr, Ki, VTr, VTi, strength, temp,
                                        por0, por1, por2, por3,
                                        poi0, poi1, poi2, poi3, Pm, Pl);
  combine_kernel<<<512, 256, 0, stream>>>(por0, por1, por2, por3,
                                          poi0, poi1, poi2, poi3, Pm, Pl, Or, Oi);
  gemm_out_kernel<<<dim3(8, 8, 2), 256, 0, stream>>>(Or, Wt + 6 * M1, bo_r, bo_i,
                                                     (float*)d_out);
}

// Round 14
// 145.131 us; speedup vs baseline: 1.2288x; 1.2288x over previous
//
#include <hip/hip_runtime.h>
#include <stdint.h>

typedef unsigned short u16;
typedef __bf16 bf16x8 __attribute__((ext_vector_type(8)));
typedef float f32x4 __attribute__((ext_vector_type(4)));
typedef unsigned int u32x4 __attribute__((ext_vector_type(4)));

__device__ __forceinline__ u16 f2bf(float f) {
  uint32_t u = __float_as_uint(f);
  u += 0x7FFFu + ((u >> 16) & 1u);   // RNE
  return (u16)(u >> 16);
}
__device__ __forceinline__ float bf2f(u16 h) {
  return __uint_as_float(((uint32_t)h) << 16);
}
__device__ __forceinline__ float fsqrt(float x) {
  float r; asm("v_sqrt_f32 %0, %1" : "=v"(r) : "v"(x)); return r;
}
__device__ __forceinline__ float fexp2(float x) {
  float r; asm("v_exp_f32 %0, %1" : "=v"(r) : "v"(x)); return r;
}
__device__ __forceinline__ void gld16(const void* g, void* lds) {
  __builtin_amdgcn_global_load_lds(
      (const __attribute__((address_space(1))) uint32_t*)g,
      (__attribute__((address_space(3))) uint32_t*)lds, 16, 0, 0);
}
__device__ __forceinline__ f32x4 mfma16(u32x4 a, u32x4 b, f32x4 c) {
  return __builtin_amdgcn_mfma_f32_16x16x32_bf16(
      __builtin_bit_cast(bf16x8, a), __builtin_bit_cast(bf16x8, b), c, 0, 0, 0);
}

// ---- fused prep: convx (X f32->bf16) + convw (W transpose+convert) + trig ----
__global__ __launch_bounds__(256) void prep_kernel(
    const float* __restrict__ real, const float* __restrict__ imag,
    u16* __restrict__ Xr, u16* __restrict__ Xi,
    const float* __restrict__ w0, const float* __restrict__ w1,
    const float* __restrict__ w2, const float* __restrict__ w3,
    const float* __restrict__ w4, const float* __restrict__ w5,
    const float* __restrict__ w6, const float* __restrict__ w7,
    u16* __restrict__ WtAll,
    const float* __restrict__ rotf, const float* __restrict__ phase,
    float* __restrict__ T) {
  __shared__ float Lt[64][65];
  int bid = blockIdx.x;
  int tid = threadIdx.x;
  if (bid < 2048) {
    // ---- convx: plain row-major f32 -> bf16 ----
    int u = bid * 256 + tid;                 // 0..524287
    int a = u >> 18;
    int r = u & 262143;                      // 8-elem unit index
    const float* src = (a ? imag : real) + (size_t)r * 8;
    u16* dst = (a ? Xi : Xr) + (size_t)r * 8;
    f32x4 v0 = *(const f32x4*)(src);
    f32x4 v1 = *(const f32x4*)(src + 4);
    union { u16 h[8]; u32x4 v; } o;
#pragma unroll
    for (int e = 0; e < 4; ++e) { o.h[e] = f2bf(v0[e]); o.h[4 + e] = f2bf(v1[e]); }
    *(u32x4*)dst = o.v;
  } else if (bid < 4096) {
    // ---- convw: W f32 [K][N] -> Wt bf16 [N][K] ----
    int wid = bid - 2048;
    int z = wid >> 8;
    int rem = wid & 255;
    int n0 = (rem & 15) * 64, k0 = (rem >> 4) * 64;
    const float* W = (z == 0) ? w0 : (z == 1) ? w1 : (z == 2) ? w2 : (z == 3) ? w3
                   : (z == 4) ? w4 : (z == 5) ? w5 : (z == 6) ? w6 : w7;
    u16* Wt = WtAll + (size_t)z * (1024 * 1024);
#pragma unroll
    for (int it = 0; it < 4; ++it) {
      int idx = it * 256 + tid;              // 0..1023 float4 units
      int kr = idx >> 4, nc = (idx & 15) * 4;
      f32x4 v = *(const f32x4*)(W + (size_t)(k0 + kr) * 1024 + n0 + nc);
#pragma unroll
      for (int e = 0; e < 4; ++e) Lt[kr][nc + e] = v[e];
    }
    __syncthreads();
#pragma unroll
    for (int it = 0; it < 2; ++it) {
      int idx = it * 256 + tid;              // 0..511
      int nr = idx >> 3, sl = idx & 7;
      union { u16 h[8]; u32x4 v; } o;
#pragma unroll
      for (int e = 0; e < 8; ++e) o.h[e] = f2bf(Lt[sl * 8 + e][nr]);
      *(u32x4*)(Wt + (size_t)(n0 + nr) * 1024 + k0 + sl * 8) = o.v;
    }
  } else {
    // ---- trig tables: rope cos/sin [1024][16], phase cos/sin [16][64] ----
    int id = (bid - 4096) * 256 + tid;
    if (id < 16384) {
      int s = id >> 4, jj = id & 15;
      float sn, cs;
      sincosf((float)s * rotf[jj], &sn, &cs);
      T[id] = cs;
      T[16384 + id] = sn;
    } else if (id < 16384 + 1024) {
      int p = id - 16384;
      float sn, cs;
      sincosf(phase[p], &sn, &cs);
      T[32768 + p] = cs;
      T[33792 + p] = sn;
    }
  }
}

// ---- 128x128 MFMA GEMM, BK=32 counted-vmcnt dbuf, bank-conflict-free ----
__device__ __forceinline__ void gemm128(const u16* __restrict__ A, const u16* __restrict__ W,
                                        const float* __restrict__ bias,
                                        u16* __restrict__ outB, float* __restrict__ outF,
                                        int bx, int by) {
  __shared__ __align__(16) u16 As[2][128 * 32];
  __shared__ __align__(16) u16 Bs[2][128 * 32];
  int tid = threadIdx.x, l = tid & 63, w = tid >> 6;
  int lr = l & 15, lh = l >> 4;
  int m0 = by * 128, n0 = bx * 128;
  int wr = w >> 1, wc = w & 1;
  f32x4 acc[4][4];
#pragma unroll
  for (int mi = 0; mi < 4; ++mi)
#pragma unroll
    for (int ni = 0; ni < 4; ++ni) acc[mi][ni] = f32x4{0.f, 0.f, 0.f, 0.f};

  // stage addressing: row = tid>>2; global source pre-swizzled, LDS linear
  int srow = tid >> 2;
  int sslot = (tid & 3) ^ ((srow >> 1) & 3);
  const u16* aA = A + (size_t)(m0 + srow) * 1024 + sslot * 8;
  const u16* aW = W + (size_t)(n0 + srow) * 1024 + sslot * 8;

  auto stage = [&](int buf, int kt) {
    const u16* pA = aA + kt * 32;
    const u16* pW = aW + kt * 32;
    char* dA = (char*)As[buf] + tid * 16;
    char* dB = (char*)Bs[buf] + tid * 16;
    gld16(pA, dA);
    gld16(pA + 64 * 1024, dA + 4096);        // c=1: +64 rows (same swizzle)
    gld16(pW, dB);
    gld16(pW + 64 * 1024, dB + 4096);
  };

  stage(0, 0);                               // prologue

  // read-side swizzled k-slot offset (row-independent)
  int xoff = (lh ^ ((lr >> 1) & 3)) << 4;

  for (int kt = 0; kt < 32; ++kt) {
    int cur = kt & 1;
    if (kt < 31) {
      stage(cur ^ 1, kt + 1);                // prefetch stays in flight
      asm volatile("s_waitcnt vmcnt(4)" ::: "memory");   // cur's 4 loads done
    } else {
      asm volatile("s_waitcnt vmcnt(0)" ::: "memory");
    }
    __builtin_amdgcn_sched_barrier(0);
    asm volatile("s_barrier" ::: "memory");  // all waves' cur loads visible

    const char* cA = (const char*)As[cur];
    const char* cB = (const char*)Bs[cur];
    u32x4 af[4], bf[4];
#pragma unroll
    for (int mi = 0; mi < 4; ++mi) {
      int row = wr * 64 + mi * 16 + lr;
      af[mi] = *(const u32x4*)(cA + row * 64 + xoff);
    }
#pragma unroll
    for (int ni = 0; ni < 4; ++ni) {
      int row = wc * 64 + ni * 16 + lr;
      bf[ni] = *(const u32x4*)(cB + row * 64 + xoff);
    }
#pragma unroll
    for (int mi = 0; mi < 4; ++mi)
#pragma unroll
      for (int ni = 0; ni < 4; ++ni)
        acc[mi][ni] = mfma16(af[mi], bf[ni], acc[mi][ni]);
    asm volatile("s_barrier" ::: "memory");  // reads done before buf overwrite
  }
#pragma unroll
  for (int ni = 0; ni < 4; ++ni) {
    int col = n0 + wc * 64 + ni * 16 + lr;
    float bv = bias[col];
#pragma unroll
    for (int mi = 0; mi < 4; ++mi)
#pragma unroll
      for (int rr = 0; rr < 4; ++rr) {
        int row = m0 + wr * 64 + mi * 16 + 4 * lh + rr;
        float v = acc[mi][ni][rr] + bv;
        if (outF) outF[(size_t)row * 1024 + col] = v;
        else      outB[(size_t)row * 1024 + col] = f2bf(v);
      }
  }
}

__global__ __launch_bounds__(256) void gemm_proj_kernel(
    const u16* __restrict__ Xr, const u16* __restrict__ Xi, const u16* __restrict__ Wt,
    const float* b0, const float* b1, const float* b2,
    const float* b3, const float* b4, const float* b5,
    u16* __restrict__ qkv) {
  // XCD-aware bijective remap: each XCD gets 96 consecutive remapped blocks
  int lin = ((int)blockIdx.z * 16 + blockIdx.y) * 8 + blockIdx.x;  // 0..767
  int nl = (lin & 7) * 96 + (lin >> 3);
  int z = nl >> 7;
  int rem = nl & 127;
  int my = rem >> 3, nx = rem & 7;
  const u16* A = (z < 3) ? Xr : Xi;
  const u16* W = Wt + (size_t)z * (1024 * 1024);
  const float* bias = (z == 0) ? b0 : (z == 1) ? b1 : (z == 2) ? b2
                    : (z == 3) ? b3 : (z == 4) ? b4 : b5;
  u16* out = qkv + (size_t)z * (2048 * 1024);
  gemm128(A, W, bias, out, nullptr, nx, my);
}

__global__ __launch_bounds__(256) void gemm_out_kernel(
    const u16* __restrict__ O, const u16* __restrict__ Wt2,
    const float* br, const float* bi, float* __restrict__ dout) {
  int lin = ((int)blockIdx.z * 16 + blockIdx.y) * 8 + blockIdx.x;  // 0..255
  int nl = (lin & 7) * 32 + (lin >> 3);
  int z = nl >> 7;
  int rem = nl & 127;
  int my = rem >> 3, nx = rem & 7;
  gemm128(O + (size_t)z * (2048 * 1024), Wt2 + (size_t)z * (1024 * 1024),
          z ? bi : br, nullptr, dout + (size_t)z * (2048 * 1024), nx, my);
}

// ---- rope + head-mix + phase (table-driven); Q/K/V relayout to [B,H,S,64] ----
__global__ __launch_bounds__(256) void transform_kernel(
    const u16* __restrict__ qkv, const float* __restrict__ ent,
    const float* __restrict__ T,
    u16* __restrict__ Qr, u16* __restrict__ Qi, u16* __restrict__ Kr,
    u16* __restrict__ Ki, u16* __restrict__ Vr, u16* __restrict__ Vi) {
  __shared__ float Lqr[16][65], Lqi[16][65], Lkr[16][65], Lki[16][65];
  __shared__ float sent[256];
  int tid = threadIdx.x;
  int bs = blockIdx.x;
  int b = bs >> 10, s = bs & 1023;
  sent[tid] = ent[tid];
  const u16* qr_raw = qkv;
  const u16* kr_raw = qkv + (size_t)1 * 2048 * 1024;
  const u16* vr_raw = qkv + (size_t)2 * 2048 * 1024;
  const u16* qi_raw = qkv + (size_t)3 * 2048 * 1024;
  const u16* ki_raw = qkv + (size_t)4 * 2048 * 1024;
  const u16* vi_raw = qkv + (size_t)5 * 2048 * 1024;
  size_t rowoff = (size_t)bs * 1024;
#pragma unroll
  for (int it = 0; it < 2; ++it) {
    int u = it * 256 + tid;                  // 0..511 : (head, pair)
    int hh = u >> 5, j = u & 31;
    int base = hh * 64 + 2 * j;
    uint32_t aqr = *(const uint32_t*)(qr_raw + rowoff + base);
    uint32_t aqi = *(const uint32_t*)(qi_raw + rowoff + base);
    uint32_t akr = *(const uint32_t*)(kr_raw + rowoff + base);
    uint32_t aki = *(const uint32_t*)(ki_raw + rowoff + base);
    float qr0 = bf2f((u16)aqr), qr1 = bf2f((u16)(aqr >> 16));
    float qi0 = bf2f((u16)aqi), qi1 = bf2f((u16)(aqi >> 16));
    float kr0 = bf2f((u16)akr), kr1 = bf2f((u16)(akr >> 16));
    float ki0 = bf2f((u16)aki), ki1 = bf2f((u16)(aki >> 16));
    if (j < 16) {
      float cs = T[s * 16 + j];
      float sn = T[16384 + s * 16 + j];
      float t0;
      t0 = qr0; qr0 = t0 * cs - qr1 * sn; qr1 = qr1 * cs + t0 * sn;
      t0 = qi0; qi0 = t0 * cs - qi1 * sn; qi1 = qi1 * cs + t0 * sn;
      t0 = kr0; kr0 = t0 * cs - kr1 * sn; kr1 = kr1 * cs + t0 * sn;
      t0 = ki0; ki0 = t0 * cs - ki1 * sn; ki1 = ki1 * cs + t0 * sn;
    }
    int d0 = 2 * j;
    Lqr[hh][d0] = qr0; Lqr[hh][d0 + 1] = qr1;
    Lqi[hh][d0] = qi0; Lqi[hh][d0 + 1] = qi1;
    Lkr[hh][d0] = kr0; Lkr[hh][d0 + 1] = kr1;
    Lki[hh][d0] = ki0; Lki[hh][d0 + 1] = ki1;
  }
  __syncthreads();
#pragma unroll
  for (int it = 0; it < 4; ++it) {
    int u = it * 256 + tid;                  // 0..1023 : (x-head, d)
    int x = u >> 6, d = u & 63;
    float mqr = 0.f, mqi = 0.f, mkr = 0.f, mki = 0.f;
#pragma unroll
    for (int hh = 0; hh < 16; ++hh) {
      float e = sent[hh * 16 + x];
      mqr += Lqr[hh][d] * e; mqi += Lqi[hh][d] * e;
      mkr += Lkr[hh][d] * e; mki += Lki[hh][d] * e;
    }
    float pc_ = T[32768 + x * 64 + d];
    float ps_ = T[33792 + x * 64 + d];
    float oqr = (mqr * pc_ - mqi * ps_) * 0.125f;  // fold 1/sqrt(64)
    float oqi = (mqr * ps_ + mqi * pc_) * 0.125f;
    float okr = mkr * pc_ - mki * ps_;
    float oki = mkr * ps_ + mki * pc_;
    size_t obase = ((size_t)(b * 16 + x) * 1024 + s) * 64;
    Qr[obase + d] = f2bf(oqr);
    Qi[obase + d] = f2bf(oqi);
    int dsw = (d & 7) | ((((d >> 3) ^ s) & 7) << 3);
    Kr[obase + dsw] = f2bf(okr);
    Ki[obase + dsw] = f2bf(oki);
  }
  {
    int u = tid;                             // 0..255 : (comp, head, slot)
    int comp = u >> 7, hh = (u >> 3) & 15, sl = u & 7;
    const u16* src = comp ? vi_raw : vr_raw;
    u16* dst = comp ? Vi : Vr;
    u32x4 vv = *(const u32x4*)(src + rowoff + hh * 64 + sl * 8);
    *(u32x4*)(dst + ((size_t)(b * 16 + hh) * 1024 + s) * 64 + sl * 8) = vv;
  }
}

// ---- V [B,H,S,64] -> VT [B,H,64,S] transposed + swizzled ----
__global__ __launch_bounds__(256) void transv_kernel(const u16* __restrict__ Vr,
                                                     const u16* __restrict__ Vi,
                                                     u16* __restrict__ VTr,
                                                     u16* __restrict__ VTi) {
  int bid = blockIdx.x;
  int comp = bid >> 9, bh = (bid >> 4) & 31, t = bid & 15;
  const u16* src = (comp ? Vi : Vr) + ((size_t)bh * 1024 + t * 64) * 64;
  u16* dst = (comp ? VTi : VTr) + (size_t)bh * 65536;
  __shared__ __align__(16) u16 Lt[64][72];
  int tid = threadIdx.x;
#pragma unroll
  for (int it = 0; it < 2; ++it) {
    int i = it * 256 + tid;
    int r = i >> 3, sl = i & 7;
    *(u32x4*)(&Lt[r][sl * 8]) = *(const u32x4*)(src + r * 64 + sl * 8);
  }
  __syncthreads();
#pragma unroll
  for (int it = 0; it < 2; ++it) {
    int i = it * 256 + tid;
    int d = i >> 3, sl = i & 7;
    union { u16 h[8]; u32x4 v; } o;
#pragma unroll
    for (int e = 0; e < 8; ++e) o.h[e] = Lt[sl * 8 + e][d];
    int sl2 = sl ^ (d & 7);
    *(u32x4*)(dst + (size_t)d * 1024 + t * 64 + sl2 * 8) = o.v;
  }
}

// ---- flash attention, uniform 4-tile chunks, partial outputs (base-2) ----
__global__ __launch_bounds__(256) void attn_kernel(
    const u16* __restrict__ Qr, const u16* __restrict__ Qi,
    const u16* __restrict__ Kr, const u16* __restrict__ Ki,
    const u16* __restrict__ VTr, const u16* __restrict__ VTi,
    const float* __restrict__ strength, const float* __restrict__ temp,
    u16* __restrict__ por0, u16* __restrict__ por1,
    u16* __restrict__ por2, u16* __restrict__ por3,
    u16* __restrict__ poi0, u16* __restrict__ poi1,
    u16* __restrict__ poi2, u16* __restrict__ poi3,
    float* __restrict__ Pm, float* __restrict__ Pl) {
  // 40KB: Kr,Ki,VrT,ViT 8KB each + 4x 2KB per-wave P
  __shared__ __align__(16) u16 smem[20480];
  char* sb = (char*)smem;
  const int PO = 32768;
  int tid = threadIdx.x, l = tid & 63, w = tid >> 6;
  int lr = l & 15, lh = l >> 4;
  // decode: XCD-local bh; chunks cc ascending = qb descending (big first)
  int id = blockIdx.x;                       // 0..1279
  int x = id & 7, j = id >> 3;               // j 0..159
  int bh = x + 8 * (j & 3);
  int cc = j >> 2;                           // 0..39
  int qb, sp;
  if (cc < 16)      { qb = 15 - (cc >> 2); sp = cc & 3; }
  else if (cc < 28) { int r = cc - 16; int q3 = r / 3; qb = 11 - q3; sp = r - 3 * q3; }
  else if (cc < 36) { int r = cc - 28; qb = 7 - (r >> 1); sp = r & 1; }
  else              { qb = 39 - cc; sp = 0; }
  int q0 = qb * 64;
  int t0 = sp * 4, t1 = min(qb + 1, t0 + 4);
  int b = bh >> 4; (void)b;
  u16* POr = (sp == 0) ? por0 : (sp == 1) ? por1 : (sp == 2) ? por2 : por3;
  u16* POi = (sp == 0) ? poi0 : (sp == 1) ? poi1 : (sp == 2) ? poi2 : poi3;

  float g = 1.f / (1.f + __expf(-strength[0]));
  float tt = fmaxf(temp[0], 0.01f);
  float gt2 = g / tt * 1.4426950408889634f;  // base-2 logit domain

  size_t qbase = ((size_t)bh * 1024 + q0 + w * 16 + lr) * 64 + lh * 8;
  u32x4 qrF[2], qiF[2], nqrF[2];
#pragma unroll
  for (int kk = 0; kk < 2; ++kk) {
    qrF[kk] = *(const u32x4*)(Qr + qbase + kk * 32);
    qiF[kk] = *(const u32x4*)(Qi + qbase + kk * 32);
    nqrF[kk] = qrF[kk] ^ 0x80008000u;
  }
  f32x4 o_r[4], o_i[4];
#pragma unroll
  for (int n = 0; n < 4; ++n) { o_r[n] = f32x4{0,0,0,0}; o_i[n] = f32x4{0,0,0,0}; }
  float m_run[4], l_run[4];
#pragma unroll
  for (int rr = 0; rr < 4; ++rr) { m_run[rr] = -__builtin_inff(); l_run[rr] = 0.f; }

  // hoisted per-wave stage pointers (advance by constant per tile)
  const u16* gK = ((w == 1) ? Ki : Kr) + ((size_t)bh * 1024 + t0 * 64) * 64 + l * 8;
  char* ldK = sb + (w == 1 ? 8192 : 0);
  const u16* gV = ((w == 3) ? VTi : VTr) + (size_t)bh * 65536 + t0 * 64 +
                  (l >> 3) * 1024 + (l & 7) * 8;
  char* ldV = sb + (w == 3 ? 24576 : 16384);

  for (int t = t0; t < t1; ++t) {
    if (w < 2) {
#pragma unroll
      for (int c = 0; c < 8; ++c) gld16(gK + c * 512, ldK + c * 1024);
      gK += 4096;
    } else {
#pragma unroll
      for (int c = 0; c < 8; ++c) gld16(gV + c * 8192, ldV + c * 1024);
      gV += 64;
    }
    __syncthreads();

    f32x4 sr[4], si[4];
#pragma unroll
    for (int n = 0; n < 4; ++n) { sr[n] = f32x4{0,0,0,0}; si[n] = f32x4{0,0,0,0}; }
    __builtin_amdgcn_s_setprio(1);
#pragma unroll
    for (int kk = 0; kk < 2; ++kk) {
#pragma unroll
      for (int n = 0; n < 4; ++n) {
        int kv = n * 16 + lr;
        int xoff = (kk * 64 + lh * 16) ^ ((kv & 7) << 4);
        u32x4 fkr = *(const u32x4*)(sb + kv * 128 + xoff);
        u32x4 fki = *(const u32x4*)(sb + 8192 + kv * 128 + xoff);
        sr[n] = mfma16(qrF[kk], fkr, sr[n]);
        sr[n] = mfma16(qiF[kk], fki, sr[n]);
        si[n] = mfma16(qiF[kk], fkr, si[n]);
        si[n] = mfma16(nqrF[kk], fki, si[n]);
      }
    }
    __builtin_amdgcn_s_setprio(0);

    float pl_[4][4], pm[4];
#pragma unroll
    for (int rr = 0; rr < 4; ++rr) pm[rr] = -__builtin_inff();
    bool diag = (t == qb);
#pragma unroll
    for (int n = 0; n < 4; ++n)
#pragma unroll
      for (int rr = 0; rr < 4; ++rr) {
        float a = sr[n][rr], ci = si[n][rr];
        float mag = fsqrt(a * a + ci * ci + 1e-6f) * gt2;
        if (diag) {
          if (n * 16 + lr > w * 16 + 4 * lh + rr) mag = -__builtin_inff();
        }
        pl_[n][rr] = mag;
        pm[rr] = fmaxf(pm[rr], mag);
      }
#pragma unroll
    for (int mk = 1; mk <= 8; mk <<= 1)
#pragma unroll
      for (int rr = 0; rr < 4; ++rr)
        pm[rr] = fmaxf(pm[rr], __shfl_xor(pm[rr], mk));

    // defer-max: skip rescale when tile max didn't grow past 8 nats (11.54 bits)
    bool defer = true;
#pragma unroll
    for (int rr = 0; rr < 4; ++rr) defer = defer && (pm[rr] - m_run[rr] <= 11.54f);
    bool noresc = __all(defer ? 1 : 0);
    float fr[4];
    if (!noresc) {
#pragma unroll
      for (int rr = 0; rr < 4; ++rr) {
        float mnew = fmaxf(m_run[rr], pm[rr]);
        fr[rr] = fexp2(m_run[rr] - mnew);
        m_run[rr] = mnew;
      }
    }
    float rs[4];
#pragma unroll
    for (int rr = 0; rr < 4; ++rr) rs[rr] = 0.f;
#pragma unroll
    for (int n = 0; n < 4; ++n)
#pragma unroll
      for (int rr = 0; rr < 4; ++rr) {
        float p = fexp2(pl_[n][rr] - m_run[rr]);
        pl_[n][rr] = p;
        rs[rr] += p;
      }
#pragma unroll
    for (int mk = 1; mk <= 8; mk <<= 1)
#pragma unroll
      for (int rr = 0; rr < 4; ++rr)
        rs[rr] += __shfl_xor(rs[rr], mk);
    if (!noresc) {
#pragma unroll
      for (int rr = 0; rr < 4; ++rr) l_run[rr] = l_run[rr] * fr[rr] + rs[rr];
#pragma unroll
      for (int n = 0; n < 4; ++n)
#pragma unroll
        for (int rr = 0; rr < 4; ++rr) { o_r[n][rr] *= fr[rr]; o_i[n][rr] *= fr[rr]; }
    } else {
#pragma unroll
      for (int rr = 0; rr < 4; ++rr) l_run[rr] += rs[rr];
    }

    char* pw = sb + PO + w * 2048;           // per-wave P tile 16x64 bf16
#pragma unroll
    for (int n = 0; n < 4; ++n)
#pragma unroll
      for (int rr = 0; rr < 4; ++rr) {
        int row = 4 * lh + rr, col = n * 16 + lr;
        int by = row * 128 + ((col & 7) * 2) + ((((col >> 3) ^ row) & 7) << 4);
        *(u16*)(pw + by) = f2bf(pl_[n][rr]);
      }
    u32x4 pf[2];
#pragma unroll
    for (int kk = 0; kk < 2; ++kk)
      pf[kk] = *(const u32x4*)(pw + lr * 128 + ((kk * 64 + lh * 16) ^ ((lr & 7) << 4)));
    __builtin_amdgcn_s_setprio(1);
#pragma unroll
    for (int kk = 0; kk < 2; ++kk)
#pragma unroll
      for (int n = 0; n < 4; ++n) {
        int dl = n * 16 + lr;
        int xoff = (kk * 64 + lh * 16) ^ ((dl & 7) << 4);
        u32x4 fvr = *(const u32x4*)(sb + 16384 + dl * 128 + xoff);
        u32x4 fvi = *(const u32x4*)(sb + 24576 + dl * 128 + xoff);
        o_r[n] = mfma16(pf[kk], fvr, o_r[n]);
        o_i[n] = mfma16(pf[kk], fvi, o_i[n]);
      }
    __builtin_amdgcn_s_setprio(0);
    __syncthreads();                         // LDS free for next tile
  }

  // epilogue: unnormalized partials (Pm in base-2 domain)
  size_t pbase = ((size_t)bh * 1024 + q0 + w * 16 + 4 * lh) * 64;
#pragma unroll
  for (int n = 0; n < 4; ++n)
#pragma unroll
    for (int rr = 0; rr < 4; ++rr) {
      POr[pbase + rr * 64 + n * 16 + lr] = f2bf(o_r[n][rr]);
      POi[pbase + rr * 64 + n * 16 + lr] = f2bf(o_i[n][rr]);
    }
  if (lr == 0) {
    size_t mbase = (size_t)sp * 32768 + (size_t)bh * 1024 + q0 + w * 16 + 4 * lh;
#pragma unroll
    for (int rr = 0; rr < 4; ++rr) {
      Pm[mbase + rr] = m_run[rr];
      Pl[mbase + rr] = l_run[rr];
    }
  }
}

// ---- combine split partials -> normalized O (base-2 Pm domain) ----
__global__ __launch_bounds__(256) void combine_kernel(
    const u16* __restrict__ por0, const u16* __restrict__ por1,
    const u16* __restrict__ por2, const u16* __restrict__ por3,
    const u16* __restrict__ poi0, const u16* __restrict__ poi1,
    const u16* __restrict__ poi2, const u16* __restrict__ poi3,
    const float* __restrict__ Pm, const float* __restrict__ Pl,
    u16* __restrict__ Or, u16* __restrict__ Oi) {
  int bid = blockIdx.x;                      // 512
  int bh = bid >> 4, rg = bid & 15;
  int b = bh >> 4, h = bh & 15;
  int ns = (rg >> 2) + 1;                    // valid splits for this q-group
  int tid = threadIdx.x;
  int row = tid >> 2, q = tid & 3;
  int s = rg * 64 + row;
  size_t ro = (size_t)bh * 1024 + s;
  const u16* PR[4] = {por0, por1, por2, por3};
  const u16* PI[4] = {poi0, poi1, poi2, poi3};
  float msp[4], lsp[4], csw[4];
  float M = -__builtin_inff();
#pragma unroll
  for (int sp = 0; sp < 4; ++sp) {
    if (sp < ns) {
      msp[sp] = Pm[ro + (size_t)sp * 32768];
      lsp[sp] = Pl[ro + (size_t)sp * 32768];
      M = fmaxf(M, msp[sp]);
    }
  }
  float lt = 0.f;
#pragma unroll
  for (int sp = 0; sp < 4; ++sp) {
    if (sp < ns) { csw[sp] = fexp2(msp[sp] - M); lt += lsp[sp] * csw[sp]; }
    else csw[sp] = 0.f;
  }
  float inv = 1.f / lt;
#pragma unroll
  for (int sp = 0; sp < 4; ++sp) csw[sp] *= inv;
  size_t obase = ro * 64;
#pragma unroll
  for (int g = 0; g < 2; ++g) {
    int d = q * 16 + g * 8;
    float accr[8], acci[8];
#pragma unroll
    for (int e = 0; e < 8; ++e) { accr[e] = 0.f; acci[e] = 0.f; }
#pragma unroll
    for (int sp = 0; sp < 4; ++sp) {
      if (sp < ns) {
        union { u16 h[8]; u32x4 v; } ar, ai;
        ar.v = *(const u32x4*)(PR[sp] + obase + d);
        ai.v = *(const u32x4*)(PI[sp] + obase + d);
#pragma unroll
        for (int e = 0; e < 8; ++e) {
          accr[e] += csw[sp] * bf2f(ar.h[e]);
          acci[e] += csw[sp] * bf2f(ai.h[e]);
        }
      }
    }
    union { u16 h[8]; u32x4 v; } outr, outi;
#pragma unroll
    for (int e = 0; e < 8; ++e) { outr.h[e] = f2bf(accr[e]); outi.h[e] = f2bf(acci[e]); }
    size_t oo = ((size_t)b * 1024 + s) * 1024 + h * 64 + d;
    *(u32x4*)(Or + oo) = outr.v;
    *(u32x4*)(Oi + oo) = outi.v;
  }
}

extern "C" void kernel_launch(void* const* d_in, const int* in_sizes, int n_in,
                              void* d_out, int out_size, void* d_ws, size_t ws_size,
                              hipStream_t stream) {
  (void)in_sizes; (void)n_in; (void)out_size; (void)ws_size;
  const float* real = (const float*)d_in[0];
  const float* imag = (const float*)d_in[1];
  const float* bq_r = (const float*)d_in[3];
  const float* bk_r = (const float*)d_in[5];
  const float* bv_r = (const float*)d_in[7];
  const float* bq_i = (const float*)d_in[9];
  const float* bk_i = (const float*)d_in[11];
  const float* bv_i = (const float*)d_in[13];
  const float* bo_r = (const float*)d_in[15];
  const float* bo_i = (const float*)d_in[17];
  const float* phase = (const float*)d_in[18];
  const float* ent = (const float*)d_in[19];
  const float* rotf = (const float*)d_in[20];
  const float* strength = (const float*)d_in[21];
  const float* temp = (const float*)d_in[22];

  u16* ws = (u16*)d_ws;
  const size_t M1 = 1024 * 1024, M2 = 2048 * 1024;
  u16* Xr  = ws;
  u16* Xi  = Xr + M2;
  u16* Wt  = Xi + M2;            // 8 * M1
  u16* qkv = Wt + 8 * M1;        // 6 * M2
  u16* Qr  = qkv + 6 * M2;
  u16* Qi  = Qr + M2;
  u16* Kr  = Qi + M2;
  u16* Ki  = Kr + M2;
  u16* Vr  = Ki + M2;
  u16* Vi  = Vr + M2;
  u16* VTr = Vi + M2;
  u16* VTi = VTr + M2;
  u16* Or  = VTi + M2;
  u16* Oi  = Or + M2;
  // overlays: partials on dead qkv/Vr/Vi; Pm/Pl on dead Xr; tables on Oi
  u16* por0 = qkv;
  u16* por1 = qkv + M2;
  u16* por2 = qkv + 2 * M2;
  u16* por3 = qkv + 3 * M2;
  u16* poi0 = qkv + 4 * M2;
  u16* poi1 = qkv + 5 * M2;
  u16* poi2 = Vr;
  u16* poi3 = Vi;
  float* Pm = (float*)Xr;
  float* Pl = Pm + 131072;
  float* TBL = (float*)Oi;       // 140KB of trig tables (dead until combine)

  prep_kernel<<<4164, 256, 0, stream>>>(
      real, imag, Xr, Xi,
      (const float*)d_in[2],  (const float*)d_in[4],  (const float*)d_in[6],
      (const float*)d_in[8],  (const float*)d_in[10], (const float*)d_in[12],
      (const float*)d_in[14], (const float*)d_in[16], Wt,
      rotf, phase, TBL);
  gemm_proj_kernel<<<dim3(8, 16, 6), 256, 0, stream>>>(Xr, Xi, Wt, bq_r, bk_r, bv_r,
                                                       bq_i, bk_i, bv_i, qkv);
  transform_kernel<<<2048, 256, 0, stream>>>(qkv, ent, TBL, Qr, Qi, Kr, Ki, Vr, Vi);
  transv_kernel<<<1024, 256, 0, stream>>>(Vr, Vi, VTr, VTi);
  attn_kernel<<<1280, 256, 0, stream>>>(Qr, Qi, Kr, Ki, VTr, VTi, strength, temp,
                                        por0, por1, por2, por3,
                                        poi0, poi1, poi2, poi3, Pm, Pl);
  combine_kernel<<<512, 256, 0, stream>>>(por0, por1, por2, por3,
                                          poi0, poi1, poi2, poi3, Pm, Pl, Or, Oi);
  gemm_out_kernel<<<dim3(8, 16, 2), 256, 0, stream>>>(Or, Wt + 6 * M1, bo_r, bo_i,
                                                      (float*)d_out);
}

// Round 15
// 144.301 us; speedup vs baseline: 1.2358x; 1.0057x over previous
//
#include <hip/hip_runtime.h>
#include <stdint.h>

typedef unsigned short u16;
typedef __bf16 bf16x8 __attribute__((ext_vector_type(8)));
typedef float f32x4 __attribute__((ext_vector_type(4)));
typedef unsigned int u32x4 __attribute__((ext_vector_type(4)));

__device__ __forceinline__ u16 f2bf(float f) {
  uint32_t u = __float_as_uint(f);
  u += 0x7FFFu + ((u >> 16) & 1u);   // RNE
  return (u16)(u >> 16);
}
__device__ __forceinline__ float bf2f(u16 h) {
  return __uint_as_float(((uint32_t)h) << 16);
}
__device__ __forceinline__ float fsqrt(float x) {
  float r; asm("v_sqrt_f32 %0, %1" : "=v"(r) : "v"(x)); return r;
}
__device__ __forceinline__ float fexp2(float x) {
  float r; asm("v_exp_f32 %0, %1" : "=v"(r) : "v"(x)); return r;
}
__device__ __forceinline__ void gld16(const void* g, void* lds) {
  __builtin_amdgcn_global_load_lds(
      (const __attribute__((address_space(1))) uint32_t*)g,
      (__attribute__((address_space(3))) uint32_t*)lds, 16, 0, 0);
}
__device__ __forceinline__ f32x4 mfma16(u32x4 a, u32x4 b, f32x4 c) {
  return __builtin_amdgcn_mfma_f32_16x16x32_bf16(
      __builtin_bit_cast(bf16x8, a), __builtin_bit_cast(bf16x8, b), c, 0, 0, 0);
}

// ---- fused prep: convx (X f32->bf16) + convw (W transpose+convert) + trig ----
__global__ __launch_bounds__(256) void prep_kernel(
    const float* __restrict__ real, const float* __restrict__ imag,
    u16* __restrict__ Xr, u16* __restrict__ Xi,
    const float* __restrict__ w0, const float* __restrict__ w1,
    const float* __restrict__ w2, const float* __restrict__ w3,
    const float* __restrict__ w4, const float* __restrict__ w5,
    const float* __restrict__ w6, const float* __restrict__ w7,
    u16* __restrict__ WtAll,
    const float* __restrict__ rotf, const float* __restrict__ phase,
    float* __restrict__ T) {
  __shared__ float Lt[64][65];
  int bid = blockIdx.x;
  int tid = threadIdx.x;
  if (bid < 2048) {
    // ---- convx: plain row-major f32 -> bf16 ----
    int u = bid * 256 + tid;                 // 0..524287
    int a = u >> 18;
    int r = u & 262143;                      // 8-elem unit index
    const float* src = (a ? imag : real) + (size_t)r * 8;
    u16* dst = (a ? Xi : Xr) + (size_t)r * 8;
    f32x4 v0 = *(const f32x4*)(src);
    f32x4 v1 = *(const f32x4*)(src + 4);
    union { u16 h[8]; u32x4 v; } o;
#pragma unroll
    for (int e = 0; e < 4; ++e) { o.h[e] = f2bf(v0[e]); o.h[4 + e] = f2bf(v1[e]); }
    *(u32x4*)dst = o.v;
  } else if (bid < 4096) {
    // ---- convw: W f32 [K][N] -> Wt bf16 [N][K] ----
    int wid = bid - 2048;
    int z = wid >> 8;
    int rem = wid & 255;
    int n0 = (rem & 15) * 64, k0 = (rem >> 4) * 64;
    const float* W = (z == 0) ? w0 : (z == 1) ? w1 : (z == 2) ? w2 : (z == 3) ? w3
                   : (z == 4) ? w4 : (z == 5) ? w5 : (z == 6) ? w6 : w7;
    u16* Wt = WtAll + (size_t)z * (1024 * 1024);
#pragma unroll
    for (int it = 0; it < 4; ++it) {
      int idx = it * 256 + tid;              // 0..1023 float4 units
      int kr = idx >> 4, nc = (idx & 15) * 4;
      f32x4 v = *(const f32x4*)(W + (size_t)(k0 + kr) * 1024 + n0 + nc);
#pragma unroll
      for (int e = 0; e < 4; ++e) Lt[kr][nc + e] = v[e];
    }
    __syncthreads();
#pragma unroll
    for (int it = 0; it < 2; ++it) {
      int idx = it * 256 + tid;              // 0..511
      int nr = idx >> 3, sl = idx & 7;
      union { u16 h[8]; u32x4 v; } o;
#pragma unroll
      for (int e = 0; e < 8; ++e) o.h[e] = f2bf(Lt[sl * 8 + e][nr]);
      *(u32x4*)(Wt + (size_t)(n0 + nr) * 1024 + k0 + sl * 8) = o.v;
    }
  } else {
    // ---- trig tables: rope cos/sin [1024][16], phase cos/sin [16][64] ----
    int id = (bid - 4096) * 256 + tid;
    if (id < 16384) {
      int s = id >> 4, jj = id & 15;
      float sn, cs;
      sincosf((float)s * rotf[jj], &sn, &cs);
      T[id] = cs;
      T[16384 + id] = sn;
    } else if (id < 16384 + 1024) {
      int p = id - 16384;
      float sn, cs;
      sincosf(phase[p], &sn, &cs);
      T[32768 + p] = cs;
      T[33792 + p] = sn;
    }
  }
}

// ---- 128x128 MFMA GEMM, BK=32 counted-vmcnt dbuf, bank-conflict-free ----
__device__ __forceinline__ void gemm128(const u16* __restrict__ A, const u16* __restrict__ W,
                                        const float* __restrict__ bias,
                                        u16* __restrict__ outB, float* __restrict__ outF,
                                        int bx, int by) {
  __shared__ __align__(16) u16 As[2][128 * 32];
  __shared__ __align__(16) u16 Bs[2][128 * 32];
  int tid = threadIdx.x, l = tid & 63, w = tid >> 6;
  int lr = l & 15, lh = l >> 4;
  int m0 = by * 128, n0 = bx * 128;
  int wr = w >> 1, wc = w & 1;
  f32x4 acc[4][4];
#pragma unroll
  for (int mi = 0; mi < 4; ++mi)
#pragma unroll
    for (int ni = 0; ni < 4; ++ni) acc[mi][ni] = f32x4{0.f, 0.f, 0.f, 0.f};

  // stage addressing: row = tid>>2; global source pre-swizzled, LDS linear
  int srow = tid >> 2;
  int sslot = (tid & 3) ^ ((srow >> 1) & 3);
  const u16* aA = A + (size_t)(m0 + srow) * 1024 + sslot * 8;
  const u16* aW = W + (size_t)(n0 + srow) * 1024 + sslot * 8;

  auto stage = [&](int buf, int kt) {
    const u16* pA = aA + kt * 32;
    const u16* pW = aW + kt * 32;
    char* dA = (char*)As[buf] + tid * 16;
    char* dB = (char*)Bs[buf] + tid * 16;
    gld16(pA, dA);
    gld16(pA + 64 * 1024, dA + 4096);        // c=1: +64 rows (same swizzle)
    gld16(pW, dB);
    gld16(pW + 64 * 1024, dB + 4096);
  };

  stage(0, 0);                               // prologue

  // read-side swizzled k-slot offset (row-independent)
  int xoff = (lh ^ ((lr >> 1) & 3)) << 4;

  for (int kt = 0; kt < 32; ++kt) {
    int cur = kt & 1;
    if (kt < 31) {
      stage(cur ^ 1, kt + 1);                // prefetch stays in flight
      asm volatile("s_waitcnt vmcnt(4)" ::: "memory");   // cur's 4 loads done
    } else {
      asm volatile("s_waitcnt vmcnt(0)" ::: "memory");
    }
    __builtin_amdgcn_sched_barrier(0);
    asm volatile("s_barrier" ::: "memory");  // all waves' cur loads visible

    const char* cA = (const char*)As[cur];
    const char* cB = (const char*)Bs[cur];
    u32x4 af[4], bf[4];
#pragma unroll
    for (int mi = 0; mi < 4; ++mi) {
      int row = wr * 64 + mi * 16 + lr;
      af[mi] = *(const u32x4*)(cA + row * 64 + xoff);
    }
#pragma unroll
    for (int ni = 0; ni < 4; ++ni) {
      int row = wc * 64 + ni * 16 + lr;
      bf[ni] = *(const u32x4*)(cB + row * 64 + xoff);
    }
#pragma unroll
    for (int mi = 0; mi < 4; ++mi)
#pragma unroll
      for (int ni = 0; ni < 4; ++ni)
        acc[mi][ni] = mfma16(af[mi], bf[ni], acc[mi][ni]);
    asm volatile("s_barrier" ::: "memory");  // reads done before buf overwrite
  }
#pragma unroll
  for (int ni = 0; ni < 4; ++ni) {
    int col = n0 + wc * 64 + ni * 16 + lr;
    float bv = bias[col];
#pragma unroll
    for (int mi = 0; mi < 4; ++mi)
#pragma unroll
      for (int rr = 0; rr < 4; ++rr) {
        int row = m0 + wr * 64 + mi * 16 + 4 * lh + rr;
        float v = acc[mi][ni][rr] + bv;
        if (outF) outF[(size_t)row * 1024 + col] = v;
        else      outB[(size_t)row * 1024 + col] = f2bf(v);
      }
  }
}

__global__ __launch_bounds__(256) void gemm_proj_kernel(
    const u16* __restrict__ Xr, const u16* __restrict__ Xi, const u16* __restrict__ Wt,
    const float* b0, const float* b1, const float* b2,
    const float* b3, const float* b4, const float* b5,
    u16* __restrict__ qkv) {
  // XCD-aware bijective remap: each XCD gets 96 consecutive remapped blocks
  int lin = ((int)blockIdx.z * 16 + blockIdx.y) * 8 + blockIdx.x;  // 0..767
  int nl = (lin & 7) * 96 + (lin >> 3);
  int z = nl >> 7;
  int rem = nl & 127;
  int my = rem >> 3, nx = rem & 7;
  const u16* A = (z < 3) ? Xr : Xi;
  const u16* W = Wt + (size_t)z * (1024 * 1024);
  const float* bias = (z == 0) ? b0 : (z == 1) ? b1 : (z == 2) ? b2
                    : (z == 3) ? b3 : (z == 4) ? b4 : b5;
  u16* out = qkv + (size_t)z * (2048 * 1024);
  gemm128(A, W, bias, out, nullptr, nx, my);
}

__global__ __launch_bounds__(256) void gemm_out_kernel(
    const u16* __restrict__ O, const u16* __restrict__ Wt2,
    const float* br, const float* bi, float* __restrict__ dout) {
  int lin = ((int)blockIdx.z * 16 + blockIdx.y) * 8 + blockIdx.x;  // 0..255
  int nl = (lin & 7) * 32 + (lin >> 3);
  int z = nl >> 7;
  int rem = nl & 127;
  int my = rem >> 3, nx = rem & 7;
  gemm128(O + (size_t)z * (2048 * 1024), Wt2 + (size_t)z * (1024 * 1024),
          z ? bi : br, nullptr, dout + (size_t)z * (2048 * 1024), nx, my);
}

// ---- rope + head-mix + phase (table-driven); Q/K relayout to [B,H,S,64] ----
// V is NOT copied here: transv reads it straight from qkv.
__global__ __launch_bounds__(256) void transform_kernel(
    const u16* __restrict__ qkv, const float* __restrict__ ent,
    const float* __restrict__ T,
    u16* __restrict__ Qr, u16* __restrict__ Qi, u16* __restrict__ Kr,
    u16* __restrict__ Ki) {
  __shared__ float Lqr[16][65], Lqi[16][65], Lkr[16][65], Lki[16][65];
  __shared__ float sent[256];
  int tid = threadIdx.x;
  int bs = blockIdx.x;
  int b = bs >> 10, s = bs & 1023;
  sent[tid] = ent[tid];
  const u16* qr_raw = qkv;
  const u16* kr_raw = qkv + (size_t)1 * 2048 * 1024;
  const u16* qi_raw = qkv + (size_t)3 * 2048 * 1024;
  const u16* ki_raw = qkv + (size_t)4 * 2048 * 1024;
  size_t rowoff = (size_t)bs * 1024;
#pragma unroll
  for (int it = 0; it < 2; ++it) {
    int u = it * 256 + tid;                  // 0..511 : (head, pair)
    int hh = u >> 5, j = u & 31;
    int base = hh * 64 + 2 * j;
    uint32_t aqr = *(const uint32_t*)(qr_raw + rowoff + base);
    uint32_t aqi = *(const uint32_t*)(qi_raw + rowoff + base);
    uint32_t akr = *(const uint32_t*)(kr_raw + rowoff + base);
    uint32_t aki = *(const uint32_t*)(ki_raw + rowoff + base);
    float qr0 = bf2f((u16)aqr), qr1 = bf2f((u16)(aqr >> 16));
    float qi0 = bf2f((u16)aqi), qi1 = bf2f((u16)(aqi >> 16));
    float kr0 = bf2f((u16)akr), kr1 = bf2f((u16)(akr >> 16));
    float ki0 = bf2f((u16)aki), ki1 = bf2f((u16)(aki >> 16));
    if (j < 16) {
      float cs = T[s * 16 + j];
      float sn = T[16384 + s * 16 + j];
      float t0;
      t0 = qr0; qr0 = t0 * cs - qr1 * sn; qr1 = qr1 * cs + t0 * sn;
      t0 = qi0; qi0 = t0 * cs - qi1 * sn; qi1 = qi1 * cs + t0 * sn;
      t0 = kr0; kr0 = t0 * cs - kr1 * sn; kr1 = kr1 * cs + t0 * sn;
      t0 = ki0; ki0 = t0 * cs - ki1 * sn; ki1 = ki1 * cs + t0 * sn;
    }
    int d0 = 2 * j;
    Lqr[hh][d0] = qr0; Lqr[hh][d0 + 1] = qr1;
    Lqi[hh][d0] = qi0; Lqi[hh][d0 + 1] = qi1;
    Lkr[hh][d0] = kr0; Lkr[hh][d0 + 1] = kr1;
    Lki[hh][d0] = ki0; Lki[hh][d0 + 1] = ki1;
  }
  __syncthreads();
#pragma unroll
  for (int it = 0; it < 4; ++it) {
    int u = it * 256 + tid;                  // 0..1023 : (x-head, d)
    int x = u >> 6, d = u & 63;
    float mqr = 0.f, mqi = 0.f, mkr = 0.f, mki = 0.f;
#pragma unroll
    for (int hh = 0; hh < 16; ++hh) {
      float e = sent[hh * 16 + x];
      mqr += Lqr[hh][d] * e; mqi += Lqi[hh][d] * e;
      mkr += Lkr[hh][d] * e; mki += Lki[hh][d] * e;
    }
    float pc_ = T[32768 + x * 64 + d];
    float ps_ = T[33792 + x * 64 + d];
    float oqr = (mqr * pc_ - mqi * ps_) * 0.125f;  // fold 1/sqrt(64)
    float oqi = (mqr * ps_ + mqi * pc_) * 0.125f;
    float okr = mkr * pc_ - mki * ps_;
    float oki = mkr * ps_ + mki * pc_;
    size_t obase = ((size_t)(b * 16 + x) * 1024 + s) * 64;
    Qr[obase + d] = f2bf(oqr);
    Qi[obase + d] = f2bf(oqi);
    int dsw = (d & 7) | ((((d >> 3) ^ s) & 7) << 3);
    Kr[obase + dsw] = f2bf(okr);
    Ki[obase + dsw] = f2bf(oki);
  }
}

// ---- V from qkv [b][s][h*64+d] -> VT [B,H,64,S] transposed + swizzled ----
__global__ __launch_bounds__(256) void transv_kernel(const u16* __restrict__ qkv,
                                                     u16* __restrict__ VTr,
                                                     u16* __restrict__ VTi) {
  int bid = blockIdx.x;
  int comp = bid >> 9, bh = (bid >> 4) & 31, t = bid & 15;
  int b = bh >> 4, h = bh & 15;
  const u16* src = qkv + (size_t)(comp ? 5 : 2) * (2048 * 1024) +
                   ((size_t)(b * 1024 + t * 64) * 1024) + h * 64;
  u16* dst = (comp ? VTi : VTr) + (size_t)bh * 65536;
  __shared__ __align__(16) u16 Lt[64][72];
  int tid = threadIdx.x;
#pragma unroll
  for (int it = 0; it < 2; ++it) {
    int i = it * 256 + tid;
    int r = i >> 3, sl = i & 7;
    *(u32x4*)(&Lt[r][sl * 8]) = *(const u32x4*)(src + (size_t)r * 1024 + sl * 8);
  }
  __syncthreads();
#pragma unroll
  for (int it = 0; it < 2; ++it) {
    int i = it * 256 + tid;
    int d = i >> 3, sl = i & 7;
    union { u16 h[8]; u32x4 v; } o;
#pragma unroll
    for (int e = 0; e < 8; ++e) o.h[e] = Lt[sl * 8 + e][d];
    int sl2 = sl ^ (d & 7);
    *(u32x4*)(dst + (size_t)d * 1024 + t * 64 + sl2 * 8) = o.v;
  }
}

// ---- flash attention, uniform 4-tile chunks, partial outputs (base-2) ----
__global__ __launch_bounds__(256) void attn_kernel(
    const u16* __restrict__ Qr, const u16* __restrict__ Qi,
    const u16* __restrict__ Kr, const u16* __restrict__ Ki,
    const u16* __restrict__ VTr, const u16* __restrict__ VTi,
    const float* __restrict__ strength, const float* __restrict__ temp,
    u16* __restrict__ por0, u16* __restrict__ por1,
    u16* __restrict__ por2, u16* __restrict__ por3,
    u16* __restrict__ poi0, u16* __restrict__ poi1,
    u16* __restrict__ poi2, u16* __restrict__ poi3,
    float* __restrict__ Pm, float* __restrict__ Pl) {
  // 40KB: Kr,Ki,VrT,ViT 8KB each + 4x 2KB per-wave P
  __shared__ __align__(16) u16 smem[20480];
  char* sb = (char*)smem;
  const int PO = 32768;
  int tid = threadIdx.x, l = tid & 63, w = tid >> 6;
  int lr = l & 15, lh = l >> 4;
  // decode: XCD-local bh; chunks cc ascending = qb descending (big first)
  int id = blockIdx.x;                       // 0..1279
  int x = id & 7, j = id >> 3;               // j 0..159
  int bh = x + 8 * (j & 3);
  int cc = j >> 2;                           // 0..39
  int qb, sp;
  if (cc < 16)      { qb = 15 - (cc >> 2); sp = cc & 3; }
  else if (cc < 28) { int r = cc - 16; int q3 = r / 3; qb = 11 - q3; sp = r - 3 * q3; }
  else if (cc < 36) { int r = cc - 28; qb = 7 - (r >> 1); sp = r & 1; }
  else              { qb = 39 - cc; sp = 0; }
  int q0 = qb * 64;
  int t0 = sp * 4, t1 = min(qb + 1, t0 + 4);
  int b = bh >> 4; (void)b;
  u16* POr = (sp == 0) ? por0 : (sp == 1) ? por1 : (sp == 2) ? por2 : por3;
  u16* POi = (sp == 0) ? poi0 : (sp == 1) ? poi1 : (sp == 2) ? poi2 : poi3;

  float g = 1.f / (1.f + __expf(-strength[0]));
  float tt = fmaxf(temp[0], 0.01f);
  float gt2 = g / tt * 1.4426950408889634f;  // base-2 logit domain

  size_t qbase = ((size_t)bh * 1024 + q0 + w * 16 + lr) * 64 + lh * 8;
  u32x4 qrF[2], qiF[2], nqrF[2];
#pragma unroll
  for (int kk = 0; kk < 2; ++kk) {
    qrF[kk] = *(const u32x4*)(Qr + qbase + kk * 32);
    qiF[kk] = *(const u32x4*)(Qi + qbase + kk * 32);
    nqrF[kk] = qrF[kk] ^ 0x80008000u;
  }
  f32x4 o_r[4], o_i[4];
#pragma unroll
  for (int n = 0; n < 4; ++n) { o_r[n] = f32x4{0,0,0,0}; o_i[n] = f32x4{0,0,0,0}; }
  float m_run[4], l_run[4];
#pragma unroll
  for (int rr = 0; rr < 4; ++rr) { m_run[rr] = -__builtin_inff(); l_run[rr] = 0.f; }

  // hoisted per-wave stage pointers (advance by constant per tile)
  const u16* gK = ((w == 1) ? Ki : Kr) + ((size_t)bh * 1024 + t0 * 64) * 64 + l * 8;
  char* ldK = sb + (w == 1 ? 8192 : 0);
  const u16* gV = ((w == 3) ? VTi : VTr) + (size_t)bh * 65536 + t0 * 64 +
                  (l >> 3) * 1024 + (l & 7) * 8;
  char* ldV = sb + (w == 3 ? 24576 : 16384);

  for (int t = t0; t < t1; ++t) {
    if (w < 2) {
#pragma unroll
      for (int c = 0; c < 8; ++c) gld16(gK + c * 512, ldK + c * 1024);
      gK += 4096;
    } else {
#pragma unroll
      for (int c = 0; c < 8; ++c) gld16(gV + c * 8192, ldV + c * 1024);
      gV += 64;
    }
    __syncthreads();

    f32x4 sr[4], si[4];
#pragma unroll
    for (int n = 0; n < 4; ++n) { sr[n] = f32x4{0,0,0,0}; si[n] = f32x4{0,0,0,0}; }
    __builtin_amdgcn_s_setprio(1);
#pragma unroll
    for (int kk = 0; kk < 2; ++kk) {
#pragma unroll
      for (int n = 0; n < 4; ++n) {
        int kv = n * 16 + lr;
        int xoff = (kk * 64 + lh * 16) ^ ((kv & 7) << 4);
        u32x4 fkr = *(const u32x4*)(sb + kv * 128 + xoff);
        u32x4 fki = *(const u32x4*)(sb + 8192 + kv * 128 + xoff);
        sr[n] = mfma16(qrF[kk], fkr, sr[n]);
        sr[n] = mfma16(qiF[kk], fki, sr[n]);
        si[n] = mfma16(qiF[kk], fkr, si[n]);
        si[n] = mfma16(nqrF[kk], fki, si[n]);
      }
    }
    __builtin_amdgcn_s_setprio(0);

    float pl_[4][4], pm[4];
#pragma unroll
    for (int rr = 0; rr < 4; ++rr) pm[rr] = -__builtin_inff();
    bool diag = (t == qb);
#pragma unroll
    for (int n = 0; n < 4; ++n)
#pragma unroll
      for (int rr = 0; rr < 4; ++rr) {
        float a = sr[n][rr], ci = si[n][rr];
        float mag = fsqrt(a * a + ci * ci + 1e-6f) * gt2;
        if (diag) {
          if (n * 16 + lr > w * 16 + 4 * lh + rr) mag = -__builtin_inff();
        }
        pl_[n][rr] = mag;
        pm[rr] = fmaxf(pm[rr], mag);
      }
#pragma unroll
    for (int mk = 1; mk <= 8; mk <<= 1)
#pragma unroll
      for (int rr = 0; rr < 4; ++rr)
        pm[rr] = fmaxf(pm[rr], __shfl_xor(pm[rr], mk));

    // defer-max: skip rescale when tile max didn't grow past 8 nats (11.54 bits)
    bool defer = true;
#pragma unroll
    for (int rr = 0; rr < 4; ++rr) defer = defer && (pm[rr] - m_run[rr] <= 11.54f);
    bool noresc = __all(defer ? 1 : 0);
    float fr[4];
    if (!noresc) {
#pragma unroll
      for (int rr = 0; rr < 4; ++rr) {
        float mnew = fmaxf(m_run[rr], pm[rr]);
        fr[rr] = fexp2(m_run[rr] - mnew);
        m_run[rr] = mnew;
      }
    }
    float rs[4];
#pragma unroll
    for (int rr = 0; rr < 4; ++rr) rs[rr] = 0.f;
#pragma unroll
    for (int n = 0; n < 4; ++n)
#pragma unroll
      for (int rr = 0; rr < 4; ++rr) {
        float p = fexp2(pl_[n][rr] - m_run[rr]);
        pl_[n][rr] = p;
        rs[rr] += p;
      }
#pragma unroll
    for (int mk = 1; mk <= 8; mk <<= 1)
#pragma unroll
      for (int rr = 0; rr < 4; ++rr)
        rs[rr] += __shfl_xor(rs[rr], mk);
    if (!noresc) {
#pragma unroll
      for (int rr = 0; rr < 4; ++rr) l_run[rr] = l_run[rr] * fr[rr] + rs[rr];
#pragma unroll
      for (int n = 0; n < 4; ++n)
#pragma unroll
        for (int rr = 0; rr < 4; ++rr) { o_r[n][rr] *= fr[rr]; o_i[n][rr] *= fr[rr]; }
    } else {
#pragma unroll
      for (int rr = 0; rr < 4; ++rr) l_run[rr] += rs[rr];
    }

    char* pw = sb + PO + w * 2048;           // per-wave P tile 16x64 bf16
#pragma unroll
    for (int n = 0; n < 4; ++n)
#pragma unroll
      for (int rr = 0; rr < 4; ++rr) {
        int row = 4 * lh + rr, col = n * 16 + lr;
        int by = row * 128 + ((col & 7) * 2) + ((((col >> 3) ^ row) & 7) << 4);
        *(u16*)(pw + by) = f2bf(pl_[n][rr]);
      }
    u32x4 pf[2];
#pragma unroll
    for (int kk = 0; kk < 2; ++kk)
      pf[kk] = *(const u32x4*)(pw + lr * 128 + ((kk * 64 + lh * 16) ^ ((lr & 7) << 4)));
    __builtin_amdgcn_s_setprio(1);
#pragma unroll
    for (int kk = 0; kk < 2; ++kk)
#pragma unroll
      for (int n = 0; n < 4; ++n) {
        int dl = n * 16 + lr;
        int xoff = (kk * 64 + lh * 16) ^ ((dl & 7) << 4);
        u32x4 fvr = *(const u32x4*)(sb + 16384 + dl * 128 + xoff);
        u32x4 fvi = *(const u32x4*)(sb + 24576 + dl * 128 + xoff);
        o_r[n] = mfma16(pf[kk], fvr, o_r[n]);
        o_i[n] = mfma16(pf[kk], fvi, o_i[n]);
      }
    __builtin_amdgcn_s_setprio(0);
    __syncthreads();                         // LDS free for next tile
  }

  // epilogue: unnormalized partials (Pm in base-2 domain)
  size_t pbase = ((size_t)bh * 1024 + q0 + w * 16 + 4 * lh) * 64;
#pragma unroll
  for (int n = 0; n < 4; ++n)
#pragma unroll
    for (int rr = 0; rr < 4; ++rr) {
      POr[pbase + rr * 64 + n * 16 + lr] = f2bf(o_r[n][rr]);
      POi[pbase + rr * 64 + n * 16 + lr] = f2bf(o_i[n][rr]);
    }
  if (lr == 0) {
    size_t mbase = (size_t)sp * 32768 + (size_t)bh * 1024 + q0 + w * 16 + 4 * lh;
#pragma unroll
    for (int rr = 0; rr < 4; ++rr) {
      Pm[mbase + rr] = m_run[rr];
      Pl[mbase + rr] = l_run[rr];
    }
  }
}

// ---- combine split partials -> normalized O (base-2 Pm domain) ----
__global__ __launch_bounds__(256) void combine_kernel(
    const u16* __restrict__ por0, const u16* __restrict__ por1,
    const u16* __restrict__ por2, const u16* __restrict__ por3,
    const u16* __restrict__ poi0, const u16* __restrict__ poi1,
    const u16* __restrict__ poi2, const u16* __restrict__ poi3,
    const float* __restrict__ Pm, const float* __restrict__ Pl,
    u16* __restrict__ Or, u16* __restrict__ Oi) {
  int bid = blockIdx.x;                      // 512
  int bh = bid >> 4, rg = bid & 15;
  int b = bh >> 4, h = bh & 15;
  int ns = (rg >> 2) + 1;                    // valid splits for this q-group
  int tid = threadIdx.x;
  int row = tid >> 2, q = tid & 3;
  int s = rg * 64 + row;
  size_t ro = (size_t)bh * 1024 + s;
  const u16* PR[4] = {por0, por1, por2, por3};
  const u16* PI[4] = {poi0, poi1, poi2, poi3};
  float msp[4], lsp[4], csw[4];
  float M = -__builtin_inff();
#pragma unroll
  for (int sp = 0; sp < 4; ++sp) {
    if (sp < ns) {
      msp[sp] = Pm[ro + (size_t)sp * 32768];
      lsp[sp] = Pl[ro + (size_t)sp * 32768];
      M = fmaxf(M, msp[sp]);
    }
  }
  float lt = 0.f;
#pragma unroll
  for (int sp = 0; sp < 4; ++sp) {
    if (sp < ns) { csw[sp] = fexp2(msp[sp] - M); lt += lsp[sp] * csw[sp]; }
    else csw[sp] = 0.f;
  }
  float inv = 1.f / lt;
#pragma unroll
  for (int sp = 0; sp < 4; ++sp) csw[sp] *= inv;
  size_t obase = ro * 64;
#pragma unroll
  for (int g = 0; g < 2; ++g) {
    int d = q * 16 + g * 8;
    float accr[8], acci[8];
#pragma unroll
    for (int e = 0; e < 8; ++e) { accr[e] = 0.f; acci[e] = 0.f; }
#pragma unroll
    for (int sp = 0; sp < 4; ++sp) {
      if (sp < ns) {
        union { u16 h[8]; u32x4 v; } ar, ai;
        ar.v = *(const u32x4*)(PR[sp] + obase + d);
        ai.v = *(const u32x4*)(PI[sp] + obase + d);
#pragma unroll
        for (int e = 0; e < 8; ++e) {
          accr[e] += csw[sp] * bf2f(ar.h[e]);
          acci[e] += csw[sp] * bf2f(ai.h[e]);
        }
      }
    }
    union { u16 h[8]; u32x4 v; } outr, outi;
#pragma unroll
    for (int e = 0; e < 8; ++e) { outr.h[e] = f2bf(accr[e]); outi.h[e] = f2bf(acci[e]); }
    size_t oo = ((size_t)b * 1024 + s) * 1024 + h * 64 + d;
    *(u32x4*)(Or + oo) = outr.v;
    *(u32x4*)(Oi + oo) = outi.v;
  }
}

extern "C" void kernel_launch(void* const* d_in, const int* in_sizes, int n_in,
                              void* d_out, int out_size, void* d_ws, size_t ws_size,
                              hipStream_t stream) {
  (void)in_sizes; (void)n_in; (void)out_size; (void)ws_size;
  const float* real = (const float*)d_in[0];
  const float* imag = (const float*)d_in[1];
  const float* bq_r = (const float*)d_in[3];
  const float* bk_r = (const float*)d_in[5];
  const float* bv_r = (const float*)d_in[7];
  const float* bq_i = (const float*)d_in[9];
  const float* bk_i = (const float*)d_in[11];
  const float* bv_i = (const float*)d_in[13];
  const float* bo_r = (const float*)d_in[15];
  const float* bo_i = (const float*)d_in[17];
  const float* phase = (const float*)d_in[18];
  const float* ent = (const float*)d_in[19];
  const float* rotf = (const float*)d_in[20];
  const float* strength = (const float*)d_in[21];
  const float* temp = (const float*)d_in[22];

  u16* ws = (u16*)d_ws;
  const size_t M1 = 1024 * 1024, M2 = 2048 * 1024;
  u16* Xr  = ws;
  u16* Xi  = Xr + M2;
  u16* Wt  = Xi + M2;            // 8 * M1
  u16* qkv = Wt + 8 * M1;        // 6 * M2
  u16* Qr  = qkv + 6 * M2;
  u16* Qi  = Qr + M2;
  u16* Kr  = Qi + M2;
  u16* Ki  = Kr + M2;
  u16* Vr  = Ki + M2;            // scratch only (poi2 overlay)
  u16* Vi  = Vr + M2;            // scratch only (poi3 overlay)
  u16* VTr = Vi + M2;
  u16* VTi = VTr + M2;
  u16* Or  = VTi + M2;
  u16* Oi  = Or + M2;
  // overlays: partials on dead qkv/Vr/Vi; Pm/Pl on dead Xr; tables on Oi
  u16* por0 = qkv;
  u16* por1 = qkv + M2;
  u16* por2 = qkv + 2 * M2;
  u16* por3 = qkv + 3 * M2;
  u16* poi0 = qkv + 4 * M2;
  u16* poi1 = qkv + 5 * M2;
  u16* poi2 = Vr;
  u16* poi3 = Vi;
  float* Pm = (float*)Xr;
  float* Pl = Pm + 131072;
  float* TBL = (float*)Oi;       // 140KB of trig tables (dead until combine)

  prep_kernel<<<4164, 256, 0, stream>>>(
      real, imag, Xr, Xi,
      (const float*)d_in[2],  (const float*)d_in[4],  (const float*)d_in[6],
      (const float*)d_in[8],  (const float*)d_in[10], (const float*)d_in[12],
      (const float*)d_in[14], (const float*)d_in[16], Wt,
      rotf, phase, TBL);
  gemm_proj_kernel<<<dim3(8, 16, 6), 256, 0, stream>>>(Xr, Xi, Wt, bq_r, bk_r, bv_r,
                                                       bq_i, bk_i, bv_i, qkv);
  transform_kernel<<<2048, 256, 0, stream>>>(qkv, ent, TBL, Qr, Qi, Kr, Ki);
  transv_kernel<<<1024, 256, 0, stream>>>(qkv, VTr, VTi);
  attn_kernel<<<1280, 256, 0, stream>>>(Qr, Qi, Kr, Ki, VTr, VTi, strength, temp,
                                        por0, por1, por2, por3,
                                        poi0, poi1, poi2, poi3, Pm, Pl);
  combine_kernel<<<512, 256, 0, stream>>>(por0, por1, por2, por3,
                                          poi0, poi1, poi2, poi3, Pm, Pl, Or, Oi);
  gemm_out_kernel<<<dim3(8, 16, 2), 256, 0, stream>>>(Or, Wt + 6 * M1, bo_r, bo_i,
                                                      (float*)d_out);
}

// Round 16
// 138.985 us; speedup vs baseline: 1.2831x; 1.0383x over previous
//
#include <hip/hip_runtime.h>
#include <stdint.h>

typedef unsigned short u16;
typedef __bf16 bf16x8 __attribute__((ext_vector_type(8)));
typedef float f32x4 __attribute__((ext_vector_type(4)));
typedef unsigned int u32x4 __attribute__((ext_vector_type(4)));

__device__ __forceinline__ u16 f2bf(float f) {
  uint32_t u = __float_as_uint(f);
  u += 0x7FFFu + ((u >> 16) & 1u);   // RNE
  return (u16)(u >> 16);
}
__device__ __forceinline__ float bf2f(u16 h) {
  return __uint_as_float(((uint32_t)h) << 16);
}
__device__ __forceinline__ float fsqrt(float x) {
  float r; asm("v_sqrt_f32 %0, %1" : "=v"(r) : "v"(x)); return r;
}
__device__ __forceinline__ float fexp2(float x) {
  float r; asm("v_exp_f32 %0, %1" : "=v"(r) : "v"(x)); return r;
}
__device__ __forceinline__ void gld16(const void* g, void* lds) {
  __builtin_amdgcn_global_load_lds(
      (const __attribute__((address_space(1))) uint32_t*)g,
      (__attribute__((address_space(3))) uint32_t*)lds, 16, 0, 0);
}
__device__ __forceinline__ f32x4 mfma16(u32x4 a, u32x4 b, f32x4 c) {
  return __builtin_amdgcn_mfma_f32_16x16x32_bf16(
      __builtin_bit_cast(bf16x8, a), __builtin_bit_cast(bf16x8, b), c, 0, 0, 0);
}

// ---- fused prep: convx (X f32->bf16) + convw (W transpose+convert) + trig ----
__global__ __launch_bounds__(256) void prep_kernel(
    const float* __restrict__ real, const float* __restrict__ imag,
    u16* __restrict__ Xr, u16* __restrict__ Xi,
    const float* __restrict__ w0, const float* __restrict__ w1,
    const float* __restrict__ w2, const float* __restrict__ w3,
    const float* __restrict__ w4, const float* __restrict__ w5,
    const float* __restrict__ w6, const float* __restrict__ w7,
    u16* __restrict__ WtAll,
    const float* __restrict__ rotf, const float* __restrict__ phase,
    float* __restrict__ T) {
  __shared__ float Lt[64][65];
  int bid = blockIdx.x;
  int tid = threadIdx.x;
  if (bid < 2048) {
    // ---- convx: plain row-major f32 -> bf16 ----
    int u = bid * 256 + tid;                 // 0..524287
    int a = u >> 18;
    int r = u & 262143;                      // 8-elem unit index
    const float* src = (a ? imag : real) + (size_t)r * 8;
    u16* dst = (a ? Xi : Xr) + (size_t)r * 8;
    f32x4 v0 = *(const f32x4*)(src);
    f32x4 v1 = *(const f32x4*)(src + 4);
    union { u16 h[8]; u32x4 v; } o;
#pragma unroll
    for (int e = 0; e < 4; ++e) { o.h[e] = f2bf(v0[e]); o.h[4 + e] = f2bf(v1[e]); }
    *(u32x4*)dst = o.v;
  } else if (bid < 4096) {
    // ---- convw: W f32 [K][N] -> Wt bf16 [N][K] ----
    int wid = bid - 2048;
    int z = wid >> 8;
    int rem = wid & 255;
    int n0 = (rem & 15) * 64, k0 = (rem >> 4) * 64;
    const float* W = (z == 0) ? w0 : (z == 1) ? w1 : (z == 2) ? w2 : (z == 3) ? w3
                   : (z == 4) ? w4 : (z == 5) ? w5 : (z == 6) ? w6 : w7;
    u16* Wt = WtAll + (size_t)z * (1024 * 1024);
#pragma unroll
    for (int it = 0; it < 4; ++it) {
      int idx = it * 256 + tid;              // 0..1023 float4 units
      int kr = idx >> 4, nc = (idx & 15) * 4;
      f32x4 v = *(const f32x4*)(W + (size_t)(k0 + kr) * 1024 + n0 + nc);
#pragma unroll
      for (int e = 0; e < 4; ++e) Lt[kr][nc + e] = v[e];
    }
    __syncthreads();
#pragma unroll
    for (int it = 0; it < 2; ++it) {
      int idx = it * 256 + tid;              // 0..511
      int nr = idx >> 3, sl = idx & 7;
      union { u16 h[8]; u32x4 v; } o;
#pragma unroll
      for (int e = 0; e < 8; ++e) o.h[e] = f2bf(Lt[sl * 8 + e][nr]);
      *(u32x4*)(Wt + (size_t)(n0 + nr) * 1024 + k0 + sl * 8) = o.v;
    }
  } else {
    // ---- trig tables: rope cos/sin [1024][16], phase cos/sin [16][64] ----
    int id = (bid - 4096) * 256 + tid;
    if (id < 16384) {
      int s = id >> 4, jj = id & 15;
      float sn, cs;
      sincosf((float)s * rotf[jj], &sn, &cs);
      T[id] = cs;
      T[16384 + id] = sn;
    } else if (id < 16384 + 1024) {
      int p = id - 16384;
      float sn, cs;
      sincosf(phase[p], &sn, &cs);
      T[32768 + p] = cs;
      T[33792 + p] = sn;
    }
  }
}

// ---- 128x128 MFMA GEMM, BK=32 counted-vmcnt dbuf, bank-conflict-free ----
__device__ __forceinline__ void gemm128(const u16* __restrict__ A, const u16* __restrict__ W,
                                        const float* __restrict__ bias,
                                        u16* __restrict__ outB, float* __restrict__ outF,
                                        int bx, int by) {
  __shared__ __align__(16) u16 As[2][128 * 32];
  __shared__ __align__(16) u16 Bs[2][128 * 32];
  int tid = threadIdx.x, l = tid & 63, w = tid >> 6;
  int lr = l & 15, lh = l >> 4;
  int m0 = by * 128, n0 = bx * 128;
  int wr = w >> 1, wc = w & 1;
  f32x4 acc[4][4];
#pragma unroll
  for (int mi = 0; mi < 4; ++mi)
#pragma unroll
    for (int ni = 0; ni < 4; ++ni) acc[mi][ni] = f32x4{0.f, 0.f, 0.f, 0.f};

  // stage addressing: row = tid>>2; global source pre-swizzled, LDS linear
  int srow = tid >> 2;
  int sslot = (tid & 3) ^ ((srow >> 1) & 3);
  const u16* aA = A + (size_t)(m0 + srow) * 1024 + sslot * 8;
  const u16* aW = W + (size_t)(n0 + srow) * 1024 + sslot * 8;

  auto stage = [&](int buf, int kt) {
    const u16* pA = aA + kt * 32;
    const u16* pW = aW + kt * 32;
    char* dA = (char*)As[buf] + tid * 16;
    char* dB = (char*)Bs[buf] + tid * 16;
    gld16(pA, dA);
    gld16(pA + 64 * 1024, dA + 4096);        // c=1: +64 rows (same swizzle)
    gld16(pW, dB);
    gld16(pW + 64 * 1024, dB + 4096);
  };

  stage(0, 0);                               // prologue

  // read-side swizzled k-slot offset (row-independent)
  int xoff = (lh ^ ((lr >> 1) & 3)) << 4;

  for (int kt = 0; kt < 32; ++kt) {
    int cur = kt & 1;
    if (kt < 31) {
      stage(cur ^ 1, kt + 1);                // prefetch stays in flight
      asm volatile("s_waitcnt vmcnt(4)" ::: "memory");   // cur's 4 loads done
    } else {
      asm volatile("s_waitcnt vmcnt(0)" ::: "memory");
    }
    __builtin_amdgcn_sched_barrier(0);
    asm volatile("s_barrier" ::: "memory");  // all waves' cur loads visible

    const char* cA = (const char*)As[cur];
    const char* cB = (const char*)Bs[cur];
    u32x4 af[4], bf[4];
#pragma unroll
    for (int mi = 0; mi < 4; ++mi) {
      int row = wr * 64 + mi * 16 + lr;
      af[mi] = *(const u32x4*)(cA + row * 64 + xoff);
    }
#pragma unroll
    for (int ni = 0; ni < 4; ++ni) {
      int row = wc * 64 + ni * 16 + lr;
      bf[ni] = *(const u32x4*)(cB + row * 64 + xoff);
    }
#pragma unroll
    for (int mi = 0; mi < 4; ++mi)
#pragma unroll
      for (int ni = 0; ni < 4; ++ni)
        acc[mi][ni] = mfma16(af[mi], bf[ni], acc[mi][ni]);
    asm volatile("s_barrier" ::: "memory");  // reads done before buf overwrite
  }
#pragma unroll
  for (int ni = 0; ni < 4; ++ni) {
    int col = n0 + wc * 64 + ni * 16 + lr;
    float bv = bias[col];
#pragma unroll
    for (int mi = 0; mi < 4; ++mi)
#pragma unroll
      for (int rr = 0; rr < 4; ++rr) {
        int row = m0 + wr * 64 + mi * 16 + 4 * lh + rr;
        float v = acc[mi][ni][rr] + bv;
        if (outF) outF[(size_t)row * 1024 + col] = v;
        else      outB[(size_t)row * 1024 + col] = f2bf(v);
      }
  }
}

__global__ __launch_bounds__(256) void gemm_proj_kernel(
    const u16* __restrict__ Xr, const u16* __restrict__ Xi, const u16* __restrict__ Wt,
    const float* b0, const float* b1, const float* b2,
    const float* b3, const float* b4, const float* b5,
    u16* __restrict__ qkv) {
  // XCD-aware bijective remap: each XCD gets 96 consecutive remapped blocks
  int lin = ((int)blockIdx.z * 16 + blockIdx.y) * 8 + blockIdx.x;  // 0..767
  int nl = (lin & 7) * 96 + (lin >> 3);
  int z = nl >> 7;
  int rem = nl & 127;
  int my = rem >> 3, nx = rem & 7;
  const u16* A = (z < 3) ? Xr : Xi;
  const u16* W = Wt + (size_t)z * (1024 * 1024);
  const float* bias = (z == 0) ? b0 : (z == 1) ? b1 : (z == 2) ? b2
                    : (z == 3) ? b3 : (z == 4) ? b4 : b5;
  u16* out = qkv + (size_t)z * (2048 * 1024);
  gemm128(A, W, bias, out, nullptr, nx, my);
}

__global__ __launch_bounds__(256) void gemm_out_kernel(
    const u16* __restrict__ O, const u16* __restrict__ Wt2,
    const float* br, const float* bi, float* __restrict__ dout) {
  int lin = ((int)blockIdx.z * 16 + blockIdx.y) * 8 + blockIdx.x;  // 0..255
  int nl = (lin & 7) * 32 + (lin >> 3);
  int z = nl >> 7;
  int rem = nl & 127;
  int my = rem >> 3, nx = rem & 7;
  gemm128(O + (size_t)z * (2048 * 1024), Wt2 + (size_t)z * (1024 * 1024),
          z ? bi : br, nullptr, dout + (size_t)z * (2048 * 1024), nx, my);
}

// ---- fused transform (rope+mix+phase, Q/K) + transv (V transpose) ----
// bid<2048: transform path; bid>=2048: transv path. Shared LDS union.
__global__ __launch_bounds__(256) void transform_kernel(
    const u16* __restrict__ qkv, const float* __restrict__ ent,
    const float* __restrict__ T,
    u16* __restrict__ Qr, u16* __restrict__ Qi, u16* __restrict__ Kr,
    u16* __restrict__ Ki, u16* __restrict__ VTr, u16* __restrict__ VTi) {
  __shared__ __align__(16) char lds_buf[17664];  // max(transform 17664, transv 9216)
  int tid = threadIdx.x;
  int bid = blockIdx.x;
  if (bid < 2048) {
    // ---- transform path ----
    float (*Lqr)[65] = (float(*)[65])(lds_buf);
    float (*Lqi)[65] = (float(*)[65])(lds_buf + 4160);
    float (*Lkr)[65] = (float(*)[65])(lds_buf + 8320);
    float (*Lki)[65] = (float(*)[65])(lds_buf + 12480);
    float* sent = (float*)(lds_buf + 16640);
    int bs = bid;
    int b = bs >> 10, s = bs & 1023;
    sent[tid] = ent[tid];
    const u16* qr_raw = qkv;
    const u16* kr_raw = qkv + (size_t)1 * 2048 * 1024;
    const u16* qi_raw = qkv + (size_t)3 * 2048 * 1024;
    const u16* ki_raw = qkv + (size_t)4 * 2048 * 1024;
    size_t rowoff = (size_t)bs * 1024;
#pragma unroll
    for (int it = 0; it < 2; ++it) {
      int u = it * 256 + tid;                // 0..511 : (head, pair)
      int hh = u >> 5, j = u & 31;
      int base = hh * 64 + 2 * j;
      uint32_t aqr = *(const uint32_t*)(qr_raw + rowoff + base);
      uint32_t aqi = *(const uint32_t*)(qi_raw + rowoff + base);
      uint32_t akr = *(const uint32_t*)(kr_raw + rowoff + base);
      uint32_t aki = *(const uint32_t*)(ki_raw + rowoff + base);
      float qr0 = bf2f((u16)aqr), qr1 = bf2f((u16)(aqr >> 16));
      float qi0 = bf2f((u16)aqi), qi1 = bf2f((u16)(aqi >> 16));
      float kr0 = bf2f((u16)akr), kr1 = bf2f((u16)(akr >> 16));
      float ki0 = bf2f((u16)aki), ki1 = bf2f((u16)(aki >> 16));
      if (j < 16) {
        float cs = T[s * 16 + j];
        float sn = T[16384 + s * 16 + j];
        float t0;
        t0 = qr0; qr0 = t0 * cs - qr1 * sn; qr1 = qr1 * cs + t0 * sn;
        t0 = qi0; qi0 = t0 * cs - qi1 * sn; qi1 = qi1 * cs + t0 * sn;
        t0 = kr0; kr0 = t0 * cs - kr1 * sn; kr1 = kr1 * cs + t0 * sn;
        t0 = ki0; ki0 = t0 * cs - ki1 * sn; ki1 = ki1 * cs + t0 * sn;
      }
      int d0 = 2 * j;
      Lqr[hh][d0] = qr0; Lqr[hh][d0 + 1] = qr1;
      Lqi[hh][d0] = qi0; Lqi[hh][d0 + 1] = qi1;
      Lkr[hh][d0] = kr0; Lkr[hh][d0 + 1] = kr1;
      Lki[hh][d0] = ki0; Lki[hh][d0 + 1] = ki1;
    }
    __syncthreads();
#pragma unroll
    for (int it = 0; it < 4; ++it) {
      int u = it * 256 + tid;                // 0..1023 : (x-head, d)
      int x = u >> 6, d = u & 63;
      float mqr = 0.f, mqi = 0.f, mkr = 0.f, mki = 0.f;
#pragma unroll
      for (int hh = 0; hh < 16; ++hh) {
        float e = sent[hh * 16 + x];
        mqr += Lqr[hh][d] * e; mqi += Lqi[hh][d] * e;
        mkr += Lkr[hh][d] * e; mki += Lki[hh][d] * e;
      }
      float pc_ = T[32768 + x * 64 + d];
      float ps_ = T[33792 + x * 64 + d];
      float oqr = (mqr * pc_ - mqi * ps_) * 0.125f;  // fold 1/sqrt(64)
      float oqi = (mqr * ps_ + mqi * pc_) * 0.125f;
      float okr = mkr * pc_ - mki * ps_;
      float oki = mkr * ps_ + mki * pc_;
      size_t obase = ((size_t)(b * 16 + x) * 1024 + s) * 64;
      Qr[obase + d] = f2bf(oqr);
      Qi[obase + d] = f2bf(oqi);
      int dsw = (d & 7) | ((((d >> 3) ^ s) & 7) << 3);
      Kr[obase + dsw] = f2bf(okr);
      Ki[obase + dsw] = f2bf(oki);
    }
  } else {
    // ---- transv path: V from qkv [b][s][h*64+d] -> VT [B,H,64,S] swizzled ----
    int vb = bid - 2048;                     // 0..1023
    int comp = vb >> 9, bh = (vb >> 4) & 31, t = vb & 15;
    int b = bh >> 4, h = bh & 15;
    const u16* src = qkv + (size_t)(comp ? 5 : 2) * (2048 * 1024) +
                     ((size_t)(b * 1024 + t * 64) * 1024) + h * 64;
    u16* dst = (comp ? VTi : VTr) + (size_t)bh * 65536;
    u16 (*Lt)[72] = (u16(*)[72])lds_buf;
#pragma unroll
    for (int it = 0; it < 2; ++it) {
      int i = it * 256 + tid;
      int r = i >> 3, sl = i & 7;
      *(u32x4*)(&Lt[r][sl * 8]) = *(const u32x4*)(src + (size_t)r * 1024 + sl * 8);
    }
    __syncthreads();
#pragma unroll
    for (int it = 0; it < 2; ++it) {
      int i = it * 256 + tid;
      int d = i >> 3, sl = i & 7;
      union { u16 h[8]; u32x4 v; } o;
#pragma unroll
      for (int e = 0; e < 8; ++e) o.h[e] = Lt[sl * 8 + e][d];
      int sl2 = sl ^ (d & 7);
      *(u32x4*)(dst + (size_t)d * 1024 + t * 64 + sl2 * 8) = o.v;
    }
  }
}

// ---- flash attention, uniform 4-tile chunks, partial outputs (base-2) ----
__global__ __launch_bounds__(256) void attn_kernel(
    const u16* __restrict__ Qr, const u16* __restrict__ Qi,
    const u16* __restrict__ Kr, const u16* __restrict__ Ki,
    const u16* __restrict__ VTr, const u16* __restrict__ VTi,
    const float* __restrict__ strength, const float* __restrict__ temp,
    u16* __restrict__ por0, u16* __restrict__ por1,
    u16* __restrict__ por2, u16* __restrict__ por3,
    u16* __restrict__ poi0, u16* __restrict__ poi1,
    u16* __restrict__ poi2, u16* __restrict__ poi3,
    float* __restrict__ Pm, float* __restrict__ Pl) {
  // 40KB: Kr,Ki,VrT,ViT 8KB each + 4x 2KB per-wave P
  __shared__ __align__(16) u16 smem[20480];
  char* sb = (char*)smem;
  const int PO = 32768;
  int tid = threadIdx.x, l = tid & 63, w = tid >> 6;
  int lr = l & 15, lh = l >> 4;
  // decode: XCD-local bh; chunks cc ascending = qb descending (big first)
  int id = blockIdx.x;                       // 0..1279
  int x = id & 7, j = id >> 3;               // j 0..159
  int bh = x + 8 * (j & 3);
  int cc = j >> 2;                           // 0..39
  int qb, sp;
  if (cc < 16)      { qb = 15 - (cc >> 2); sp = cc & 3; }
  else if (cc < 28) { int r = cc - 16; int q3 = r / 3; qb = 11 - q3; sp = r - 3 * q3; }
  else if (cc < 36) { int r = cc - 28; qb = 7 - (r >> 1); sp = r & 1; }
  else              { qb = 39 - cc; sp = 0; }
  int q0 = qb * 64;
  int t0 = sp * 4, t1 = min(qb + 1, t0 + 4);
  int b = bh >> 4; (void)b;
  u16* POr = (sp == 0) ? por0 : (sp == 1) ? por1 : (sp == 2) ? por2 : por3;
  u16* POi = (sp == 0) ? poi0 : (sp == 1) ? poi1 : (sp == 2) ? poi2 : poi3;

  float g = 1.f / (1.f + __expf(-strength[0]));
  float tt = fmaxf(temp[0], 0.01f);
  float gt2 = g / tt * 1.4426950408889634f;  // base-2 logit domain

  size_t qbase = ((size_t)bh * 1024 + q0 + w * 16 + lr) * 64 + lh * 8;
  u32x4 qrF[2], qiF[2], nqrF[2];
#pragma unroll
  for (int kk = 0; kk < 2; ++kk) {
    qrF[kk] = *(const u32x4*)(Qr + qbase + kk * 32);
    qiF[kk] = *(const u32x4*)(Qi + qbase + kk * 32);
    nqrF[kk] = qrF[kk] ^ 0x80008000u;
  }
  f32x4 o_r[4], o_i[4];
#pragma unroll
  for (int n = 0; n < 4; ++n) { o_r[n] = f32x4{0,0,0,0}; o_i[n] = f32x4{0,0,0,0}; }
  float m_run[4], l_run[4];
#pragma unroll
  for (int rr = 0; rr < 4; ++rr) { m_run[rr] = -__builtin_inff(); l_run[rr] = 0.f; }

  // hoisted per-wave stage pointers (advance by constant per tile)
  const u16* gK = ((w == 1) ? Ki : Kr) + ((size_t)bh * 1024 + t0 * 64) * 64 + l * 8;
  char* ldK = sb + (w == 1 ? 8192 : 0);
  const u16* gV = ((w == 3) ? VTi : VTr) + (size_t)bh * 65536 + t0 * 64 +
                  (l >> 3) * 1024 + (l & 7) * 8;
  char* ldV = sb + (w == 3 ? 24576 : 16384);

  for (int t = t0; t < t1; ++t) {
    if (w < 2) {
#pragma unroll
      for (int c = 0; c < 8; ++c) gld16(gK + c * 512, ldK + c * 1024);
      gK += 4096;
    } else {
#pragma unroll
      for (int c = 0; c < 8; ++c) gld16(gV + c * 8192, ldV + c * 1024);
      gV += 64;
    }
    __syncthreads();

    f32x4 sr[4], si[4];
#pragma unroll
    for (int n = 0; n < 4; ++n) { sr[n] = f32x4{0,0,0,0}; si[n] = f32x4{0,0,0,0}; }
    __builtin_amdgcn_s_setprio(1);
#pragma unroll
    for (int kk = 0; kk < 2; ++kk) {
#pragma unroll
      for (int n = 0; n < 4; ++n) {
        int kv = n * 16 + lr;
        int xoff = (kk * 64 + lh * 16) ^ ((kv & 7) << 4);
        u32x4 fkr = *(const u32x4*)(sb + kv * 128 + xoff);
        u32x4 fki = *(const u32x4*)(sb + 8192 + kv * 128 + xoff);
        sr[n] = mfma16(qrF[kk], fkr, sr[n]);
        sr[n] = mfma16(qiF[kk], fki, sr[n]);
        si[n] = mfma16(qiF[kk], fkr, si[n]);
        si[n] = mfma16(nqrF[kk], fki, si[n]);
      }
    }
    __builtin_amdgcn_s_setprio(0);

    float pl_[4][4], pm[4];
#pragma unroll
    for (int rr = 0; rr < 4; ++rr) pm[rr] = -__builtin_inff();
    bool diag = (t == qb);
#pragma unroll
    for (int n = 0; n < 4; ++n)
#pragma unroll
      for (int rr = 0; rr < 4; ++rr) {
        float a = sr[n][rr], ci = si[n][rr];
        float mag = fsqrt(a * a + ci * ci + 1e-6f) * gt2;
        if (diag) {
          if (n * 16 + lr > w * 16 + 4 * lh + rr) mag = -__builtin_inff();
        }
        pl_[n][rr] = mag;
        pm[rr] = fmaxf(pm[rr], mag);
      }
#pragma unroll
    for (int mk = 1; mk <= 8; mk <<= 1)
#pragma unroll
      for (int rr = 0; rr < 4; ++rr)
        pm[rr] = fmaxf(pm[rr], __shfl_xor(pm[rr], mk));

    // defer-max: skip rescale when tile max didn't grow past 8 nats (11.54 bits)
    bool defer = true;
#pragma unroll
    for (int rr = 0; rr < 4; ++rr) defer = defer && (pm[rr] - m_run[rr] <= 11.54f);
    bool noresc = __all(defer ? 1 : 0);
    float fr[4];
    if (!noresc) {
#pragma unroll
      for (int rr = 0; rr < 4; ++rr) {
        float mnew = fmaxf(m_run[rr], pm[rr]);
        fr[rr] = fexp2(m_run[rr] - mnew);
        m_run[rr] = mnew;
      }
    }
    float rs[4];
#pragma unroll
    for (int rr = 0; rr < 4; ++rr) rs[rr] = 0.f;
#pragma unroll
    for (int n = 0; n < 4; ++n)
#pragma unroll
      for (int rr = 0; rr < 4; ++rr) {
        float p = fexp2(pl_[n][rr] - m_run[rr]);
        pl_[n][rr] = p;
        rs[rr] += p;
      }
#pragma unroll
    for (int mk = 1; mk <= 8; mk <<= 1)
#pragma unroll
      for (int rr = 0; rr < 4; ++rr)
        rs[rr] += __shfl_xor(rs[rr], mk);
    if (!noresc) {
#pragma unroll
      for (int rr = 0; rr < 4; ++rr) l_run[rr] = l_run[rr] * fr[rr] + rs[rr];
#pragma unroll
      for (int n = 0; n < 4; ++n)
#pragma unroll
        for (int rr = 0; rr < 4; ++rr) { o_r[n][rr] *= fr[rr]; o_i[n][rr] *= fr[rr]; }
    } else {
#pragma unroll
      for (int rr = 0; rr < 4; ++rr) l_run[rr] += rs[rr];
    }

    char* pw = sb + PO + w * 2048;           // per-wave P tile 16x64 bf16
#pragma unroll
    for (int n = 0; n < 4; ++n)
#pragma unroll
      for (int rr = 0; rr < 4; ++rr) {
        int row = 4 * lh + rr, col = n * 16 + lr;
        int by = row * 128 + ((col & 7) * 2) + ((((col >> 3) ^ row) & 7) << 4);
        *(u16*)(pw + by) = f2bf(pl_[n][rr]);
      }
    u32x4 pf[2];
#pragma unroll
    for (int kk = 0; kk < 2; ++kk)
      pf[kk] = *(const u32x4*)(pw + lr * 128 + ((kk * 64 + lh * 16) ^ ((lr & 7) << 4)));
    __builtin_amdgcn_s_setprio(1);
#pragma unroll
    for (int kk = 0; kk < 2; ++kk)
#pragma unroll
      for (int n = 0; n < 4; ++n) {
        int dl = n * 16 + lr;
        int xoff = (kk * 64 + lh * 16) ^ ((dl & 7) << 4);
        u32x4 fvr = *(const u32x4*)(sb + 16384 + dl * 128 + xoff);
        u32x4 fvi = *(const u32x4*)(sb + 24576 + dl * 128 + xoff);
        o_r[n] = mfma16(pf[kk], fvr, o_r[n]);
        o_i[n] = mfma16(pf[kk], fvi, o_i[n]);
      }
    __builtin_amdgcn_s_setprio(0);
    __syncthreads();                         // LDS free for next tile
  }

  // epilogue: unnormalized partials (Pm in base-2 domain)
  size_t pbase = ((size_t)bh * 1024 + q0 + w * 16 + 4 * lh) * 64;
#pragma unroll
  for (int n = 0; n < 4; ++n)
#pragma unroll
    for (int rr = 0; rr < 4; ++rr) {
      POr[pbase + rr * 64 + n * 16 + lr] = f2bf(o_r[n][rr]);
      POi[pbase + rr * 64 + n * 16 + lr] = f2bf(o_i[n][rr]);
    }
  if (lr == 0) {
    size_t mbase = (size_t)sp * 32768 + (size_t)bh * 1024 + q0 + w * 16 + 4 * lh;
#pragma unroll
    for (int rr = 0; rr < 4; ++rr) {
      Pm[mbase + rr] = m_run[rr];
      Pl[mbase + rr] = l_run[rr];
    }
  }
}

// ---- combine split partials -> normalized O (base-2 Pm domain) ----
__global__ __launch_bounds__(256) void combine_kernel(
    const u16* __restrict__ por0, const u16* __restrict__ por1,
    const u16* __restrict__ por2, const u16* __restrict__ por3,
    const u16* __restrict__ poi0, const u16* __restrict__ poi1,
    const u16* __restrict__ poi2, const u16* __restrict__ poi3,
    const float* __restrict__ Pm, const float* __restrict__ Pl,
    u16* __restrict__ Or, u16* __restrict__ Oi) {
  int bid = blockIdx.x;                      // 512
  int bh = bid >> 4, rg = bid & 15;
  int b = bh >> 4, h = bh & 15;
  int ns = (rg >> 2) + 1;                    // valid splits for this q-group
  int tid = threadIdx.x;
  int row = tid >> 2, q = tid & 3;
  int s = rg * 64 + row;
  size_t ro = (size_t)bh * 1024 + s;
  const u16* PR[4] = {por0, por1, por2, por3};
  const u16* PI[4] = {poi0, poi1, poi2, poi3};
  float msp[4], lsp[4], csw[4];
  float M = -__builtin_inff();
#pragma unroll
  for (int sp = 0; sp < 4; ++sp) {
    if (sp < ns) {
      msp[sp] = Pm[ro + (size_t)sp * 32768];
      lsp[sp] = Pl[ro + (size_t)sp * 32768];
      M = fmaxf(M, msp[sp]);
    }
  }
  float lt = 0.f;
#pragma unroll
  for (int sp = 0; sp < 4; ++sp) {
    if (sp < ns) { csw[sp] = fexp2(msp[sp] - M); lt += lsp[sp] * csw[sp]; }
    else csw[sp] = 0.f;
  }
  float inv = 1.f / lt;
#pragma unroll
  for (int sp = 0; sp < 4; ++sp) csw[sp] *= inv;
  size_t obase = ro * 64;
#pragma unroll
  for (int g = 0; g < 2; ++g) {
    int d = q * 16 + g * 8;
    float accr[8], acci[8];
#pragma unroll
    for (int e = 0; e < 8; ++e) { accr[e] = 0.f; acci[e] = 0.f; }
#pragma unroll
    for (int sp = 0; sp < 4; ++sp) {
      if (sp < ns) {
        union { u16 h[8]; u32x4 v; } ar, ai;
        ar.v = *(const u32x4*)(PR[sp] + obase + d);
        ai.v = *(const u32x4*)(PI[sp] + obase + d);
#pragma unroll
        for (int e = 0; e < 8; ++e) {
          accr[e] += csw[sp] * bf2f(ar.h[e]);
          acci[e] += csw[sp] * bf2f(ai.h[e]);
        }
      }
    }
    union { u16 h[8]; u32x4 v; } outr, outi;
#pragma unroll
    for (int e = 0; e < 8; ++e) { outr.h[e] = f2bf(accr[e]); outi.h[e] = f2bf(acci[e]); }
    size_t oo = ((size_t)b * 1024 + s) * 1024 + h * 64 + d;
    *(u32x4*)(Or + oo) = outr.v;
    *(u32x4*)(Oi + oo) = outi.v;
  }
}

extern "C" void kernel_launch(void* const* d_in, const int* in_sizes, int n_in,
                              void* d_out, int out_size, void* d_ws, size_t ws_size,
                              hipStream_t stream) {
  (void)in_sizes; (void)n_in; (void)out_size; (void)ws_size;
  const float* real = (const float*)d_in[0];
  const float* imag = (const float*)d_in[1];
  const float* bq_r = (const float*)d_in[3];
  const float* bk_r = (const float*)d_in[5];
  const float* bv_r = (const float*)d_in[7];
  const float* bq_i = (const float*)d_in[9];
  const float* bk_i = (const float*)d_in[11];
  const float* bv_i = (const float*)d_in[13];
  const float* bo_r = (const float*)d_in[15];
  const float* bo_i = (const float*)d_in[17];
  const float* phase = (const float*)d_in[18];
  const float* ent = (const float*)d_in[19];
  const float* rotf = (const float*)d_in[20];
  const float* strength = (const float*)d_in[21];
  const float* temp = (const float*)d_in[22];

  u16* ws = (u16*)d_ws;
  const size_t M1 = 1024 * 1024, M2 = 2048 * 1024;
  u16* Xr  = ws;
  u16* Xi  = Xr + M2;
  u16* Wt  = Xi + M2;            // 8 * M1
  u16* qkv = Wt + 8 * M1;        // 6 * M2
  u16* Qr  = qkv + 6 * M2;
  u16* Qi  = Qr + M2;
  u16* Kr  = Qi + M2;
  u16* Ki  = Kr + M2;
  u16* Vr  = Ki + M2;            // scratch only (poi2 overlay)
  u16* Vi  = Vr + M2;            // scratch only (poi3 overlay)
  u16* VTr = Vi + M2;
  u16* VTi = VTr + M2;
  u16* Or  = VTi + M2;
  u16* Oi  = Or + M2;
  // overlays: partials on dead qkv/Vr/Vi; Pm/Pl on dead Xr; tables on Oi
  u16* por0 = qkv;
  u16* por1 = qkv + M2;
  u16* por2 = qkv + 2 * M2;
  u16* por3 = qkv + 3 * M2;
  u16* poi0 = qkv + 4 * M2;
  u16* poi1 = qkv + 5 * M2;
  u16* poi2 = Vr;
  u16* poi3 = Vi;
  float* Pm = (float*)Xr;
  float* Pl = Pm + 131072;
  float* TBL = (float*)Oi;       // 140KB of trig tables (dead until combine)

  prep_kernel<<<4164, 256, 0, stream>>>(
      real, imag, Xr, Xi,
      (const float*)d_in[2],  (const float*)d_in[4],  (const float*)d_in[6],
      (const float*)d_in[8],  (const float*)d_in[10], (const float*)d_in[12],
      (const float*)d_in[14], (const float*)d_in[16], Wt,
      rotf, phase, TBL);
  gemm_proj_kernel<<<dim3(8, 16, 6), 256, 0, stream>>>(Xr, Xi, Wt, bq_r, bk_r, bv_r,
                                                       bq_i, bk_i, bv_i, qkv);
  transform_kernel<<<3072, 256, 0, stream>>>(qkv, ent, TBL, Qr, Qi, Kr, Ki, VTr, VTi);
  attn_kernel<<<1280, 256, 0, stream>>>(Qr, Qi, Kr, Ki, VTr, VTi, strength, temp,
                                        por0, por1, por2, por3,
                                        poi0, poi1, poi2, poi3, Pm, Pl);
  combine_kernel<<<512, 256, 0, stream>>>(por0, por1, por2, por3,
                                          poi0, poi1, poi2, poi3, Pm, Pl, Or, Oi);
  gemm_out_kernel<<<dim3(8, 16, 2), 256, 0, stream>>>(Or, Wt + 6 * M1, bo_r, bo_i,
                                                      (float*)d_out);
}